// Round 9
// baseline (191.000 us; speedup 1.0000x reference)
//
#include <hip/hip_runtime.h>
#include <hip/hip_bf16.h>
#include <math.h>

#define BB 8
#define LL 160000
#define CC 4
#define NFFT 320
#define HOP 160
#define FB 161          // rfft bins
#define TT 1001         // frames
#define TP 1024         // padded frames per batch (t-slots) for STFT GEMM
#define RBLK 128        // stats blocks per batch
#define PI_D 3.14159265358979323846
#define NPAD 160320     // reflect-padded samples per (b,c): p in [-160, 160159]

#define KWARM 4         // warm-up frames; tail weight 0.05^5 ~ 3e-7 rel << bf16 error floor (4.9e-4)

#define GM 16016        // irfft GEMM M = 2*BB*TT rows (beam,b,t)
#define KSEC 352        // irfft padded K per split-section (322 used)
#define LDK 704         // irfft A/Bt leading dim = 2 sections
#define KT 11           // irfft K-tiles of 32 per section
// R22: k_gstft 128x192 tile (was 128x128). Grid 768->512 blocks = exactly 2
//      serial/CU (was 3); MFMA/kt/wave 24->36; per-CU barriers 60->40. LDS 80KB
//      (2 x 40KB buffers, flat 5-DMA staging: Ah|Al|Bh|Bl regions; swizzle formula
//      (s&3)^((s>>3)&3) holds in all regions). vmcnt(5) steady. Register split
//      (R20 lesson, 128-VGPR cap): {A,Bh reads} -> 24 acc-rotating MFMAs -> {Bl
//      reads} -> barrier2 -> STG -> 12 hl MFMAs; peak live ~88. Per-acc order
//      hh,lh,hl preserved (bit-exact).
// R21: k_gen exact mod-320 + f32 sincosf; REVERTED R20's per-acc MFMA grouping
//      (dependent chains stall matrix pipe at 2 blk/CU — keep acc-rotating).
// R20: k_scan full-strip 2 outputs/thread (-40% UPD); k_gemm 3-buffer ring.
// R19: anorm coalesced; scan direct stores + Q-form (scale-invariant solve).
// R14 lesson (direct-global gather, 47->115us): LDS staging is a latency-decoupling
// pipeline, not just a cache — do not remove it.
// LIFETIME NOTE (R13 bug): Bt/Bts must NOT live in the S region — k_gstft overwrites
// ALL of S. Both live in d_out's head (dead until k_ola fully overwrites at the end).

typedef __attribute__((ext_vector_type(8))) short bf16x8;
typedef __attribute__((ext_vector_type(4))) float f32x4;

__device__ __forceinline__ void ldsdma16(const short* g, short* l){
    // wave-level DMA: per-lane global src, wave-uniform LDS base + lane*16B
    __builtin_amdgcn_global_load_lds((const __attribute__((address_space(1))) void*)g,
                                     (__attribute__((address_space(3))) void*)l, 16, 0, 0);
}

__device__ __forceinline__ float2 cmulf(float2 a, float2 b){           // a*b
    return make_float2(a.x*b.x - a.y*b.y, a.x*b.y + a.y*b.x);
}
__device__ __forceinline__ float2 cmulcj(float2 a, float2 b){          // a*conj(b)
    return make_float2(a.x*b.x + a.y*b.y, a.y*b.x - a.x*b.y);
}
__device__ __forceinline__ float2 cjmul(float2 a, float2 b){           // conj(a)*b
    return make_float2(a.x*b.x + a.y*b.y, a.x*b.y - a.y*b.x);
}
__device__ __forceinline__ float2 csub(float2 a, float2 b){ return make_float2(a.x-b.x, a.y-b.y); }
__device__ __forceinline__ float2 cscale(float2 a, float s){ return make_float2(a.x*s, a.y*s); }
__device__ __forceinline__ float2 cdivf(float2 a, float2 b){           // a/b
    float inv = 1.0f/(b.x*b.x + b.y*b.y);
    return make_float2((a.x*b.x + a.y*b.y)*inv, (a.y*b.x - a.x*b.y)*inv);
}
__device__ __forceinline__ short bf_hi(float v){
    __hip_bfloat16 h = __float2bfloat16(v);
    short s; __builtin_memcpy(&s, &h, 2); return s;
}
__device__ __forceinline__ short bf_lo(float v){
    __hip_bfloat16 h = __float2bfloat16(v);
    float r = v - __bfloat162float(h);
    __hip_bfloat16 l = __float2bfloat16(r);
    short s; __builtin_memcpy(&s, &l, 2); return s;
}

// ---------- fused table generator: htab | Bts (STFT B) | Bt (irfft B) ----------
// R21: big sections use exact mod-320 int reduction + f32 sincosf.
__global__ void k_gen(const float* __restrict__ win, float* __restrict__ htab,
                      short* __restrict__ Bts, short* __restrict__ Bt){
    int gid = blockIdx.x*256 + threadIdx.x;
    const float W0 = (float)(2.0*PI_D/320.0);
    if (gid < 2*FB*CC){
        int i = gid;
        int c = i & 3;
        int k = (i >> 2) % FB;
        int m = i / (FB*CC);
        double coef = 2.0*PI_D*50.0*0.027*sin(40.0*PI_D/180.0)/340.0;
        double sgn = (m == 0) ? -1.0 : 1.0;
        double ph = sgn*coef*(double)k*(double)c;
        double s, c2;
        sincos(ph, &s, &c2);
        ((float2*)htab)[i] = make_float2((float)c2, (float)s);
        return;
    }
    gid -= 2*FB*CC;
    if (gid < 384*640){
        int col = gid / 640, kk = gid % 640;
        int n = (kk >= 320) ? kk - 320 : kk;
        int sec = (kk >= 320) ? 1 : 0;
        float v = 0.f;
        if (col < 2*FB){
            int k = col >> 1;
            int mr = (k*n) % 320;                    // exact reduction
            float s, co; sincosf(W0*(float)mr, &s, &co);
            v = win[n] * ((col & 1) ? -s : co);
        }
        Bts[gid] = sec ? bf_lo(v) : bf_hi(v);
        return;
    }
    gid -= 384*640;
    if (gid < NFFT*LDK){
        int n = gid / LDK, kk = gid % LDK;
        int sec = (kk >= KSEC) ? 1 : 0;
        int kk2 = kk - (sec ? KSEC : 0);
        float v = 0.f;
        if (kk2 < 2*FB){
            int bin = kk2 >> 1;
            float c = ((bin == 0 || bin == 160) ? 1.0f : 2.0f) * (1.0f/320.0f);
            int mr = (bin*n) % 320;                  // exact reduction
            float s, co; sincosf(W0*(float)mr, &s, &co);
            v = (kk2 & 1) ? -c*s : c*co;
        }
        Bt[(size_t)n*LDK + kk] = sec ? bf_lo(v) : bf_hi(v);
    }
}

// ---------- stage 1: per-(b,chunk) partial {sum4, min4, max4} ----------
__global__ __launch_bounds__(256) void k_stats1(const float* __restrict__ in, float* __restrict__ part){
    __shared__ float4 s4[256];
    __shared__ float4 mn4[256];
    __shared__ float4 mx4[256];
    int b = blockIdx.x / RBLK, chunk = blockIdx.x % RBLK;
    int tid = threadIdx.x;
    const float4* p = (const float4*)(in + (size_t)b*LL*CC);
    const int per = LL / RBLK;
    int start = chunk*per;
    float4 s  = make_float4(0.f,0.f,0.f,0.f);
    float4 mn = make_float4( 3.4e38f, 3.4e38f, 3.4e38f, 3.4e38f);
    float4 mx = make_float4(-3.4e38f,-3.4e38f,-3.4e38f,-3.4e38f);
    for (int i = start + tid; i < start + per; i += 256){
        float4 v = p[i];
        s.x += v.x; s.y += v.y; s.z += v.z; s.w += v.w;
        mn.x = fminf(mn.x, v.x); mn.y = fminf(mn.y, v.y); mn.z = fminf(mn.z, v.z); mn.w = fminf(mn.w, v.w);
        mx.x = fmaxf(mx.x, v.x); mx.y = fmaxf(mx.y, v.y); mx.z = fmaxf(mx.z, v.z); mx.w = fmaxf(mx.w, v.w);
    }
    s4[tid] = s; mn4[tid] = mn; mx4[tid] = mx;
    __syncthreads();
    for (int st = 128; st >= 1; st >>= 1){
        if (tid < st){
            float4 a = s4[tid], c = s4[tid+st];
            s4[tid] = make_float4(a.x+c.x, a.y+c.y, a.z+c.z, a.w+c.w);
            float4 d = mn4[tid], e = mn4[tid+st];
            mn4[tid] = make_float4(fminf(d.x,e.x), fminf(d.y,e.y), fminf(d.z,e.z), fminf(d.w,e.w));
            float4 f = mx4[tid], g = mx4[tid+st];
            mx4[tid] = make_float4(fmaxf(f.x,g.x), fmaxf(f.y,g.y), fmaxf(f.z,g.z), fmaxf(f.w,g.w));
        }
        __syncthreads();
    }
    if (tid == 0){
        float* dst = part + (size_t)(b*RBLK + chunk)*12;
        float4 a = s4[0], d = mn4[0], f = mx4[0];
        dst[0]=a.x; dst[1]=a.y; dst[2]=a.z; dst[3]=a.w;
        dst[4]=d.x; dst[5]=d.y; dst[6]=d.z; dst[7]=d.w;
        dst[8]=f.x; dst[9]=f.y; dst[10]=f.z; dst[11]=f.w;
    }
}

// ---------- stage 2: finalize mean + invmax per batch ----------
__global__ __launch_bounds__(128) void k_stats2(const float* __restrict__ part,
                                                float* __restrict__ mean, float* __restrict__ invmax){
    __shared__ float4 s4[128];
    __shared__ float4 mn4[128];
    __shared__ float4 mx4[128];
    int b = blockIdx.x, tid = threadIdx.x;
    const float* src = part + (size_t)(b*RBLK + tid)*12;
    s4[tid]  = make_float4(src[0], src[1], src[2], src[3]);
    mn4[tid] = make_float4(src[4], src[5], src[6], src[7]);
    mx4[tid] = make_float4(src[8], src[9], src[10], src[11]);
    __syncthreads();
    for (int st = 64; st >= 1; st >>= 1){
        if (tid < st){
            float4 a = s4[tid], c = s4[tid+st];
            s4[tid] = make_float4(a.x+c.x, a.y+c.y, a.z+c.z, a.w+c.w);
            float4 d = mn4[tid], e = mn4[tid+st];
            mn4[tid] = make_float4(fminf(d.x,e.x), fminf(d.y,e.y), fminf(d.z,e.z), fminf(d.w,e.w));
            float4 f = mx4[tid], g = mx4[tid+st];
            mx4[tid] = make_float4(fmaxf(f.x,g.x), fmaxf(f.y,g.y), fmaxf(f.z,g.z), fmaxf(f.w,g.w));
        }
        __syncthreads();
    }
    if (tid == 0){
        float4 sum = s4[0], mn = mn4[0], mx = mx4[0];
        float m0 = sum.x*(1.0f/LL), m1 = sum.y*(1.0f/LL), m2 = sum.z*(1.0f/LL), m3 = sum.w*(1.0f/LL);
        mean[b*4+0]=m0; mean[b*4+1]=m1; mean[b*4+2]=m2; mean[b*4+3]=m3;
        float a0 = fmaxf(mx.x - m0, m0 - mn.x);
        float a1 = fmaxf(mx.y - m1, m1 - mn.y);
        float a2 = fmaxf(mx.z - m2, m2 - mn.z);
        float a3 = fmaxf(mx.w - m3, m3 - mn.w);
        invmax[b] = 1.0f / fmaxf(fmaxf(a0, a1), fmaxf(a2, a3));
    }
}

// ---------- A-normalize (R19): coalesced — thread = 8 consecutive samples x 4 channels ----------
__global__ __launch_bounds__(256) void k_anorm(const float* __restrict__ in,
        const float* __restrict__ mean, const float* __restrict__ invmax,
        short* __restrict__ Ahi, short* __restrict__ Alo){
    int gid = blockIdx.x*256 + threadIdx.x;
    if (gid >= BB*(NPAD/8)) return;
    int p8 = gid % (NPAD/8);
    int b  = gid / (NPAD/8);
    float4 mc = *(const float4*)&mean[b*4];
    float iv = invmax[b];
    const float4* px = (const float4*)(in + (size_t)b*LL*CC);   // [LL][4ch]
    bf16x8 h0{}, h1{}, h2{}, h3{}, l0{}, l1{}, l2{}, l3{};
    #pragma unroll
    for (int j = 0; j < 8; ++j){
        int p = p8*8 + j - 160;
        int m2 = p < 0 ? -p : (p >= LL ? 2*LL - 2 - p : p);
        float4 v = px[m2];
        float v0 = (v.x - mc.x)*iv, v1 = (v.y - mc.y)*iv;
        float v2 = (v.z - mc.z)*iv, v3 = (v.w - mc.w)*iv;
        h0[j] = bf_hi(v0); l0[j] = bf_lo(v0);
        h1[j] = bf_hi(v1); l1[j] = bf_lo(v1);
        h2[j] = bf_hi(v2); l2[j] = bf_lo(v2);
        h3[j] = bf_hi(v3); l3[j] = bf_lo(v3);
    }
    size_t o = (size_t)(b*4)*NPAD + (size_t)p8*8;
    *(bf16x8*)&Ahi[o]          = h0;  *(bf16x8*)&Alo[o]          = l0;
    *(bf16x8*)&Ahi[o +   NPAD] = h1;  *(bf16x8*)&Alo[o +   NPAD] = l1;
    *(bf16x8*)&Ahi[o + 2*NPAD] = h2;  *(bf16x8*)&Alo[o + 2*NPAD] = l2;
    *(bf16x8*)&Ahi[o + 3*NPAD] = h3;  *(bf16x8*)&Alo[o + 3*NPAD] = l3;
}

// ---------- STFT as MFMA GEMM, R22: 128x192 tile, 8 waves (4x2; 32x96/wave) ----------
// LDS buffer (40KB): flat [Ah 4096 | Al 4096 | Bh 6144 | Bl 6144] shorts, rows of 32
// shorts, chunk-swizzled slot' = chunk ^ ((row>>1)&3). Staged by 5 ldsdma16/thread
// over flat slots s = j*512 + tid (region formulas verified: (s&3)^((s>>3)&3) is the
// swizzled chunk in every region). MFMA order: acc-rotating, per-acc hh,lh,hl
// (bit-exact vs 128-col version). Register split: {A,Bh reads} -> 24 MFMAs ->
// {Bl reads} -> barrier2 -> STG -> 12 hl MFMAs (peak live ~88 VGPR).
// S out layout: complex S[b][k][h][t] (h = channel-pair), float4 per (b,k,h,t)
__global__ __launch_bounds__(512, 4) void k_gstft(const short* __restrict__ Ahi, const short* __restrict__ Alo,
        const short* __restrict__ Bts, float* __restrict__ S){
    __shared__ short stage[40960];           // 80 KB: 2 buffers x 20480 shorts
    int tid = threadIdx.x;
    int row0 = blockIdx.x*128;               // over b*TP*CC rows
    int col0 = blockIdx.y*192;               // 2 col-blocks cover 384 >= 322
    int b  = row0 >> 12;                     // TP*CC = 4096 rows per batch
    int t0 = (row0 & 4095) >> 2;             // in {0,32,...,992} — always < TT
    int wave = tid >> 6, lane = tid & 63;
    int wm = wave >> 1, wn = wave & 1;       // 4x2 wave grid: 32 rows x 96 cols each
    int l15 = lane & 15, quad = lane >> 4;
    // ---- staging: 5 flat-slot DMAs per thread; chunk = (tid&3)^((tid>>3)&3) ----
    int chunk = (tid & 3) ^ ((tid >> 3) & 3);
    int tq4 = tid >> 2;
    // j=0/1: A rows 0..127 (tid>>2), channel = row&3
    int rowA = tq4;                          // tid in [0,512)
    int tls = t0 + (rowA >> 2); if (tls >= TT) tls = TT - 1;
    size_t gao = (size_t)(b*4 + (rowA & 3))*NPAD + (size_t)tls*160 + chunk*8;
    const short* src0 = Ahi + gao;
    const short* src1 = Alo + gao;
    // j=2: Bh rows 0..127 ; j=3: tid<256 -> Bh rows 128..191, else Bl rows 0..63
    // j=4: Bl rows 64..191
    const short* src2 = Bts + (size_t)(col0 + tq4)*640 + chunk*8;
    const short* src3 = (tid < 256)
        ? Bts + (size_t)(col0 + 128 + tq4)*640 + chunk*8
        : Bts + (size_t)(col0 + ((tid - 256) >> 2))*640 + 320 + chunk*8;
    const short* src4 = Bts + (size_t)(col0 + 64 + tq4)*640 + 320 + chunk*8;
    short* lw = stage + wave*512;            // + j*4096 + buffer offset
    // ---- read addresses (swizzle (row>>1)&3 == (l15>>1)&3 for all row patterns) ----
    int sw  = (l15 >> 1) & 3;
    int c0r = (quad ^ sw) * 8;
    int ra0 = (wm*32 + l15)*32 + c0r;        // A frag 0; frag 1 at +512; Al at +4096
    int rbB = (wn*96 + l15)*32 + c0r;        // B frag j at +8192 (hi) / +14336 (lo) + j*512
    f32x4 c00 = {0.f,0.f,0.f,0.f}, c01 = c00, c02 = c00, c03 = c00, c04 = c00, c05 = c00;
    f32x4 c10 = c00, c11 = c00, c12 = c00, c13 = c00, c14 = c00, c15 = c00;

    #define STG(kt_, off_) do{ int ko_ = (kt_)*32; \
        ldsdma16(src0 + ko_, lw + (off_));          \
        ldsdma16(src1 + ko_, lw + (off_) + 4096);   \
        ldsdma16(src2 + ko_, lw + (off_) + 8192);   \
        ldsdma16(src3 + ko_, lw + (off_) + 12288);  \
        ldsdma16(src4 + ko_, lw + (off_) + 16384);  \
    }while(0)

    STG(0, 0);                               // 2-deep prologue
    STG(1, 20480);
    #pragma unroll
    for (int kt = 0; kt < 10; ++kt){
        int offc = (kt & 1) ? 20480 : 0;
        if (kt < 9) asm volatile("s_waitcnt vmcnt(5)" ::: "memory");
        else        asm volatile("s_waitcnt vmcnt(0)" ::: "memory");
        __builtin_amdgcn_s_barrier();        // buf[kt&1] ready
        bf16x8 a0h = *(bf16x8*)&stage[offc + ra0];
        bf16x8 a1h = *(bf16x8*)&stage[offc + ra0 + 512];
        bf16x8 a0l = *(bf16x8*)&stage[offc + 4096 + ra0];
        bf16x8 a1l = *(bf16x8*)&stage[offc + 4096 + ra0 + 512];
        bf16x8 b0h = *(bf16x8*)&stage[offc + 8192 + rbB];
        bf16x8 b1h = *(bf16x8*)&stage[offc + 8192 + rbB + 512];
        bf16x8 b2h = *(bf16x8*)&stage[offc + 8192 + rbB + 1024];
        bf16x8 b3h = *(bf16x8*)&stage[offc + 8192 + rbB + 1536];
        bf16x8 b4h = *(bf16x8*)&stage[offc + 8192 + rbB + 2048];
        bf16x8 b5h = *(bf16x8*)&stage[offc + 8192 + rbB + 2560];
        // group1: hh + lh, acc-rotating (compiler orders MFMAs after these loads)
        c00 = __builtin_amdgcn_mfma_f32_16x16x32_bf16(a0h, b0h, c00, 0, 0, 0);
        c01 = __builtin_amdgcn_mfma_f32_16x16x32_bf16(a0h, b1h, c01, 0, 0, 0);
        c02 = __builtin_amdgcn_mfma_f32_16x16x32_bf16(a0h, b2h, c02, 0, 0, 0);
        c03 = __builtin_amdgcn_mfma_f32_16x16x32_bf16(a0h, b3h, c03, 0, 0, 0);
        c04 = __builtin_amdgcn_mfma_f32_16x16x32_bf16(a0h, b4h, c04, 0, 0, 0);
        c05 = __builtin_amdgcn_mfma_f32_16x16x32_bf16(a0h, b5h, c05, 0, 0, 0);
        c10 = __builtin_amdgcn_mfma_f32_16x16x32_bf16(a1h, b0h, c10, 0, 0, 0);
        c11 = __builtin_amdgcn_mfma_f32_16x16x32_bf16(a1h, b1h, c11, 0, 0, 0);
        c12 = __builtin_amdgcn_mfma_f32_16x16x32_bf16(a1h, b2h, c12, 0, 0, 0);
        c13 = __builtin_amdgcn_mfma_f32_16x16x32_bf16(a1h, b3h, c13, 0, 0, 0);
        c14 = __builtin_amdgcn_mfma_f32_16x16x32_bf16(a1h, b4h, c14, 0, 0, 0);
        c15 = __builtin_amdgcn_mfma_f32_16x16x32_bf16(a1h, b5h, c15, 0, 0, 0);
        c00 = __builtin_amdgcn_mfma_f32_16x16x32_bf16(a0l, b0h, c00, 0, 0, 0);
        c01 = __builtin_amdgcn_mfma_f32_16x16x32_bf16(a0l, b1h, c01, 0, 0, 0);
        c02 = __builtin_amdgcn_mfma_f32_16x16x32_bf16(a0l, b2h, c02, 0, 0, 0);
        c03 = __builtin_amdgcn_mfma_f32_16x16x32_bf16(a0l, b3h, c03, 0, 0, 0);
        c04 = __builtin_amdgcn_mfma_f32_16x16x32_bf16(a0l, b4h, c04, 0, 0, 0);
        c05 = __builtin_amdgcn_mfma_f32_16x16x32_bf16(a0l, b5h, c05, 0, 0, 0);
        c10 = __builtin_amdgcn_mfma_f32_16x16x32_bf16(a1l, b0h, c10, 0, 0, 0);
        c11 = __builtin_amdgcn_mfma_f32_16x16x32_bf16(a1l, b1h, c11, 0, 0, 0);
        c12 = __builtin_amdgcn_mfma_f32_16x16x32_bf16(a1l, b2h, c12, 0, 0, 0);
        c13 = __builtin_amdgcn_mfma_f32_16x16x32_bf16(a1l, b3h, c13, 0, 0, 0);
        c14 = __builtin_amdgcn_mfma_f32_16x16x32_bf16(a1l, b4h, c14, 0, 0, 0);
        c15 = __builtin_amdgcn_mfma_f32_16x16x32_bf16(a1l, b5h, c15, 0, 0, 0);
        // Bl reads (Bh registers die above -> peak pressure stays low)
        bf16x8 b0l = *(bf16x8*)&stage[offc + 14336 + rbB];
        bf16x8 b1l = *(bf16x8*)&stage[offc + 14336 + rbB + 512];
        bf16x8 b2l = *(bf16x8*)&stage[offc + 14336 + rbB + 1024];
        bf16x8 b3l = *(bf16x8*)&stage[offc + 14336 + rbB + 1536];
        bf16x8 b4l = *(bf16x8*)&stage[offc + 14336 + rbB + 2048];
        bf16x8 b5l = *(bf16x8*)&stage[offc + 14336 + rbB + 2560];
        asm volatile("s_waitcnt lgkmcnt(0)" ::: "memory");
        __builtin_amdgcn_sched_barrier(0);   // rule #18: pin ALL buffer reads before reuse barrier
        __builtin_amdgcn_s_barrier();        // all waves done reading buf[kt&1]
        if (kt < 8) STG(kt+2, offc);         // overwrite just-freed buffer
        // group2: hl
        c00 = __builtin_amdgcn_mfma_f32_16x16x32_bf16(a0h, b0l, c00, 0, 0, 0);
        c01 = __builtin_amdgcn_mfma_f32_16x16x32_bf16(a0h, b1l, c01, 0, 0, 0);
        c02 = __builtin_amdgcn_mfma_f32_16x16x32_bf16(a0h, b2l, c02, 0, 0, 0);
        c03 = __builtin_amdgcn_mfma_f32_16x16x32_bf16(a0h, b3l, c03, 0, 0, 0);
        c04 = __builtin_amdgcn_mfma_f32_16x16x32_bf16(a0h, b4l, c04, 0, 0, 0);
        c05 = __builtin_amdgcn_mfma_f32_16x16x32_bf16(a0h, b5l, c05, 0, 0, 0);
        c10 = __builtin_amdgcn_mfma_f32_16x16x32_bf16(a1h, b0l, c10, 0, 0, 0);
        c11 = __builtin_amdgcn_mfma_f32_16x16x32_bf16(a1h, b1l, c11, 0, 0, 0);
        c12 = __builtin_amdgcn_mfma_f32_16x16x32_bf16(a1h, b2l, c12, 0, 0, 0);
        c13 = __builtin_amdgcn_mfma_f32_16x16x32_bf16(a1h, b3l, c13, 0, 0, 0);
        c14 = __builtin_amdgcn_mfma_f32_16x16x32_bf16(a1h, b4l, c14, 0, 0, 0);
        c15 = __builtin_amdgcn_mfma_f32_16x16x32_bf16(a1h, b5l, c15, 0, 0, 0);
    }
    #undef STG
    // ---- epilogue: shfl-pair assembly, direct global store (no LDS) ----
    int tq  = t0 + wm*8 + quad;
    int kgb = (col0 >> 1) + wn*48 + (l15 >> 1);
    int h   = l15 & 1;
    float4* S4 = (float4*)S;
    #define EPI(cf, i_, j_) do{ \
        int t = tq + 4*(i_); \
        int kg = kgb + 8*(j_); \
        if (t < TT && kg < FB){ \
            float p0 = __shfl_xor(cf[0], 1); \
            float p1 = __shfl_xor(cf[1], 1); \
            float p2 = __shfl_xor(cf[2], 1); \
            float p3 = __shfl_xor(cf[3], 1); \
            float4 v = h ? make_float4(p2, cf[2], p3, cf[3]) \
                         : make_float4(cf[0], p0, cf[1], p1); \
            S4[((size_t)((b*FB + kg)*2 + h))*TT + t] = v; \
        } \
    }while(0)
    EPI(c00, 0, 0); EPI(c01, 0, 1); EPI(c02, 0, 2); EPI(c03, 0, 3); EPI(c04, 0, 4); EPI(c05, 0, 5);
    EPI(c10, 1, 0); EPI(c11, 1, 1); EPI(c12, 1, 2); EPI(c13, 1, 3); EPI(c14, 1, 4); EPI(c15, 1, 5);
    #undef EPI
}

// covariance recurrence, original weighted form (first-frame handling): R = a*R + wg*outer(X)
#define UPD(first) do{ \
    float aa = (first) ? 0.f : 0.05f; float wg = (first) ? 1.f : 0.95f; \
    float y0x=wg*x0.x, y0y=wg*x0.y, y1x=wg*x1.x, y1y=wg*x1.y; \
    float y2x=wg*x2.x, y2y=wg*x2.y, y3x=wg*x3.x, y3y=wg*x3.y; \
    d0 = aa*d0 + y0x*x0.x + y0y*x0.y; \
    d1 = aa*d1 + y1x*x1.x + y1y*x1.y; \
    d2 = aa*d2 + y2x*x2.x + y2y*x2.y; \
    d3 = aa*d3 + y3x*x3.x + y3y*x3.y; \
    r10.x = aa*r10.x + y1x*x0.x + y1y*x0.y;  r10.y = aa*r10.y + y1y*x0.x - y1x*x0.y; \
    r20.x = aa*r20.x + y2x*x0.x + y2y*x0.y;  r20.y = aa*r20.y + y2y*x0.x - y2x*x0.y; \
    r30.x = aa*r30.x + y3x*x0.x + y3y*x0.y;  r30.y = aa*r30.y + y3y*x0.x - y3x*x0.y; \
    r21.x = aa*r21.x + y2x*x1.x + y2y*x1.y;  r21.y = aa*r21.y + y2y*x1.x - y2x*x1.y; \
    r31.x = aa*r31.x + y3x*x1.x + y3y*x1.y;  r31.y = aa*r31.y + y3y*x1.x - y3x*x1.y; \
    r32.x = aa*r32.x + y3x*x2.x + y3y*x2.y;  r32.y = aa*r32.y + y3y*x2.x - y3x*x2.y; \
}while(0)

// Q-form (R19): Q = 0.05*Q + outer(X); Q = R/0.95 exactly when no first-frame is in
// the truncated window. The solve is scale-invariant in R -> outputs identical.
#define UPDQ do{ \
    d0 = 0.05f*d0 + x0.x*x0.x + x0.y*x0.y; \
    d1 = 0.05f*d1 + x1.x*x1.x + x1.y*x1.y; \
    d2 = 0.05f*d2 + x2.x*x2.x + x2.y*x2.y; \
    d3 = 0.05f*d3 + x3.x*x3.x + x3.y*x3.y; \
    r10.x = 0.05f*r10.x + x1.x*x0.x + x1.y*x0.y;  r10.y = 0.05f*r10.y + x1.y*x0.x - x1.x*x0.y; \
    r20.x = 0.05f*r20.x + x2.x*x0.x + x2.y*x0.y;  r20.y = 0.05f*r20.y + x2.y*x0.x - x2.x*x0.y; \
    r30.x = 0.05f*r30.x + x3.x*x0.x + x3.y*x0.y;  r30.y = 0.05f*r30.y + x3.y*x0.x - x3.x*x0.y; \
    r21.x = 0.05f*r21.x + x2.x*x1.x + x2.y*x1.y;  r21.y = 0.05f*r21.y + x2.y*x1.x - x2.x*x1.y; \
    r31.x = 0.05f*r31.x + x3.x*x1.x + x3.y*x1.y;  r31.y = 0.05f*r31.y + x3.y*x1.x - x3.x*x1.y; \
    r32.x = 0.05f*r32.x + x3.x*x2.x + x3.y*x2.y;  r32.y = 0.05f*r32.y + x3.y*x2.x - x3.x*x2.y; \
}while(0)

// ---------- scan (R20): full-strip (1 block per (b,f)), 512 threads, 2 outputs/thread ----------
__global__ __launch_bounds__(512) void k_scan(const float* __restrict__ S, const float* __restrict__ htab,
                      float* __restrict__ S1, float* __restrict__ S2){
    __shared__ float4 tile[2016];     // swizzled full strip (2*TT=2002 used; swz stays in-group)
    int bf = blockIdx.x;              // b*FB + f
    int f  = bf % FB;
    int tid = threadIdx.x;
    const float4* P0 = (const float4*)S + (size_t)(bf*2)*TT;
    const float4* P1 = P0 + TT;
    for (int i = tid; i < 2*TT; i += 512){
        int tt = i >> 1;
        tile[i ^ ((i>>4)&7)] = (i & 1) ? P1[tt] : P0[tt];   // interleave planes into tile
    }
    __syncthreads();
    int t0 = tid*2;
    if (t0 < TT){
        const float2* hp = (const float2*)htab;
        float2 ha0 = hp[f*4+0], ha1 = hp[f*4+1], ha2 = hp[f*4+2], ha3 = hp[f*4+3];
        float2 hb0 = hp[(FB+f)*4+0], hb1 = hp[(FB+f)*4+1], hb2 = hp[(FB+f)*4+2], hb3 = hp[(FB+f)*4+3];
        float d0=0,d1=0,d2=0,d3=0;
        float2 r10={0,0}, r20={0,0}, r30={0,0}, r21={0,0}, r31={0,0}, r32={0,0};
        float2 x0, x1, x2, x3;
        #define LOADX(tau_) do{ int i0_ = 2*(tau_); \
            float4 v0_ = tile[i0_ ^ ((i0_>>4)&7)]; \
            float4 v1_ = tile[(i0_+1) ^ (((i0_+1)>>4)&7)]; \
            x0 = make_float2(v0_.x, v0_.y); x1 = make_float2(v0_.z, v0_.w); \
            x2 = make_float2(v1_.x, v1_.y); x3 = make_float2(v1_.z, v1_.w); \
        }while(0)
        bool qform = (t0 >= KWARM + 1);   // no frame-0 special in any window
        int ts = t0 - KWARM; if (ts < 0) ts = 0;
        if (qform){
            #pragma unroll
            for (int u = 0; u < KWARM; ++u){ LOADX(ts + u); UPDQ; }
        } else {
            for (int tau = 0; tau < t0; ++tau){ LOADX(tau); UPD(tau == 0); }
        }
        float2* S1g = (float2*)S1 + (size_t)bf*TT;
        float2* S2g = (float2*)S2 + (size_t)bf*TT;
        #pragma unroll
        for (int j = 0; j < 2; ++j){
            int t = t0 + j;
            if (t >= TT) break;
            LOADX(t);
            if (qform) UPDQ; else UPD(t == 0);
            float trc = d0 + d1 + d2 + d3;
            float lam = trc * 0.25f;
            float e0 = d0 + lam, e1 = d1 + lam, e2 = d2 + lam, e3 = d3 + lam;
            float detP = e0*e1 - (r10.x*r10.x + r10.y*r10.y);
            float2 w00 = csub(cscale(r20, e1), cmulf(r10, r21));
            float2 w01 = csub(cscale(r30, e1), cmulf(r10, r31));
            float2 w10 = csub(cscale(r21, e0), cjmul(r10, r20));
            float2 w11 = csub(cscale(r31, e0), cjmul(r10, r30));
            float2 va = cjmul(r30, w00), vb = cjmul(r31, w10);
            float2 V10 = make_float2(va.x + vb.x, -(va.y + vb.y));
            float reV00 = r20.x*w00.x + r20.y*w00.y + r21.x*w10.x + r21.y*w10.y;
            float reV11 = r30.x*w01.x + r30.y*w01.y + r31.x*w11.x + r31.y*w11.y;
            float t00 = detP*e2 - reV00;
            float t11 = detP*e3 - reV11;
            float2 t10 = csub(cscale(r32, detP), V10);
            float detT = t00*t11 - (t10.x*t10.x + t10.y*t10.y);
            #pragma unroll
            for (int m = 0; m < 2; ++m){
                float2 h0 = m ? hb0 : ha0;
                float2 h1 = m ? hb1 : ha1;
                float2 h2 = m ? hb2 : ha2;
                float2 h3 = m ? hb3 : ha3;
                float2 g0 = csub(cscale(h0, e1), cjmul(r10, h1));
                float2 g1 = csub(cscale(h1, e0), cmulf(r10, h0));
                float2 ta = cmulf(r20, g0), tb = cmulf(r21, g1);
                float2 hh0 = make_float2(detP*h2.x - ta.x - tb.x, detP*h2.y - ta.y - tb.y);
                ta = cmulf(r30, g0); tb = cmulf(r31, g1);
                float2 hh1 = make_float2(detP*h3.x - ta.x - tb.x, detP*h3.y - ta.y - tb.y);
                float2 y20 = csub(cscale(hh0, t11), cjmul(t10, hh1));
                float2 y21 = csub(cscale(hh1, t00), cmulf(t10, hh0));
                float2 u20 = cscale(y20, detP), u21 = cscale(y21, detP);
                ta = cmulcj(y20, r20); tb = cmulcj(y21, r30);
                float2 q0 = make_float2(detT*h0.x - ta.x - tb.x, detT*h0.y - ta.y - tb.y);
                ta = cmulcj(y20, r21); tb = cmulcj(y21, r31);
                float2 q1 = make_float2(detT*h1.x - ta.x - tb.x, detT*h1.y - ta.y - tb.y);
                float2 u10 = csub(cscale(q0, e1), cjmul(r10, q1));
                float2 u11 = csub(cscale(q1, e0), cmulf(r10, q0));
                float2 den = cjmul(h0, u10), tmp;
                tmp = cjmul(h1, u11); den.x += tmp.x; den.y += tmp.y;
                tmp = cjmul(h2, u20); den.x += tmp.x; den.y += tmp.y;
                tmp = cjmul(h3, u21); den.x += tmp.x; den.y += tmp.y;
                float2 num = cjmul(u10, x0);
                tmp = cjmul(u11, x1); num.x += tmp.x; num.y += tmp.y;
                tmp = cjmul(u20, x2); num.x += tmp.x; num.y += tmp.y;
                tmp = cjmul(u21, x3); num.x += tmp.x; num.y += tmp.y;
                float2 s = cdivf(num, make_float2(den.x, -den.y));
                if (m) S2g[t] = s; else S1g[t] = s;
            }
        }
        #undef LOADX
    }
}

// ---------- pack v2 (R8-verified): coalesced LDS transpose. block = (rb, 32-t tile) ----------
__global__ __launch_bounds__(256) void k_pack(const float* __restrict__ S1, const float* __restrict__ S2,
                                              short* __restrict__ A){
    __shared__ short tile[32*708];        // 45,312 B; row = t-in-tile, col = kk (hi 0..351 | lo 352..703)
    int bid = blockIdx.x;                 // rb*32 + tb
    int tb = bid & 31, rb = bid >> 5;
    int t0 = tb*32;
    int beam = rb >> 3, b = rb & 7;
    const float2* Sp = (const float2*)(beam ? S2 : S1) + (size_t)b*FB*TT;
    int tid = threadIdx.x;
    for (int idx = tid; idx < 32*176; idx += 256){
        int bin = idx >> 5, tq = idx & 31;
        int t = t0 + tq;
        float2 s = make_float2(0.f, 0.f);
        if (bin < FB && t < TT) s = Sp[(size_t)bin*TT + t];
        int c0 = 2*bin;
        tile[tq*708 + c0]            = bf_hi(s.x);
        tile[tq*708 + c0 + 1]        = bf_hi(s.y);
        tile[tq*708 + KSEC + c0]     = bf_lo(s.x);
        tile[tq*708 + KSEC + c0 + 1] = bf_lo(s.y);
    }
    __syncthreads();
    for (int idx = tid; idx < 32*176; idx += 256){
        int tq = idx / 176, k4 = idx % 176;
        int t = t0 + tq;
        if (t < TT)
            *(short4*)&A[(size_t)(rb*TT + t)*LDK + k4*4] = *(short4*)&tile[tq*708 + k4*4];
    }
}

// ---------- irfft MFMA GEMM (R20): 3-buffer ring, ONE barrier per step ----------
__global__ __launch_bounds__(512, 4) void k_gemm(const short* __restrict__ A, const short* __restrict__ Bt,
                                                 float* __restrict__ C){
    __shared__ short sb2[24576];           // 48 KB: 3 buffers x (A|B) x 4096 shorts
    int tid = threadIdx.x;
    int row0 = blockIdx.x * 128;
    int col0 = blockIdx.y * 128;
    int wave = tid >> 6, lane = tid & 63;
    int wm = wave >> 1, wn = wave & 1;     // 4x2 wave grid: 32 rows x 64 cols each
    int l15 = lane & 15, quad = lane >> 4;
    bool wlive = (col0 + wn*64) < NFFT;    // y=2,wn=1 waves are fully past NFFT
    // staging (per lane)
    int rowS  = wave*16 + (lane >> 2);
    int chunk = (lane & 3) ^ ((lane >> 3) & 3);
    int grS = row0 + rowS; if (grS >= GM) grS = GM - 1;       // clamp; stores guarded
    int grB = col0 + rowS; if (grB >= NFFT) grB = NFFT - 1;   // clamp; cols >=320 unused
    const short* gA = A  + (size_t)grS*LDK + chunk*8;
    const short* gB = Bt + (size_t)grB*LDK + chunk*8;
    short* lA = sb2 + wave*512;
    // reads
    int sw  = (l15 >> 1) & 3;
    int c0r = (quad ^ sw) * 8;
    int ra0 = (wm*32 + l15)*32 + c0r;      // frag 1 at +512
    int rb0 = (wn*64 + l15)*32 + c0r;      // frag j at +j*512
    f32x4 c00 = {0.f,0.f,0.f,0.f}, c01 = c00, c02 = c00, c03 = c00;
    f32x4 c10 = c00, c11 = c00, c12 = c00, c13 = c00;

    #define KOF(s_, ka_, kb_) { int sg_ = ((s_) >= 22) ? 2 : ((s_) >= 11) ? 1 : 0; \
        int kt_ = (s_) - sg_*11; \
        ka_ = ((sg_ == 1) ? KSEC : 0) + kt_*32; \
        kb_ = ((sg_ == 2) ? KSEC : 0) + kt_*32; }
    #define STG2(s_, off_) do{ int ka_, kb_; KOF(s_, ka_, kb_); \
        ldsdma16(gA + ka_, lA + (off_));        \
        ldsdma16(gB + kb_, lA + (off_) + 4096); \
    }while(0)

    STG2(0, 0);                            // 2-deep prologue into ring slots 0,1
    STG2(1, 8192);
    #pragma unroll
    for (int s = 0; s < 33; ++s){
        int offc = (s % 3) * 8192;
        if (s < 32) asm volatile("s_waitcnt vmcnt(2)" ::: "memory");
        else        asm volatile("s_waitcnt vmcnt(0)" ::: "memory");
        __builtin_amdgcn_s_barrier();      // buf[s%3] ready; also: all s-1 reads done
        if (s < 31) STG2(s+2, ((s+2) % 3) * 8192);   // writes buf[(s-1)%3] — freed above
        bf16x8 a0{}, a1{}, b0{}, b1{}, b2{}, b3{};
        if (wlive){
            a0 = *(bf16x8*)&sb2[offc + ra0];
            a1 = *(bf16x8*)&sb2[offc + ra0 + 512];
            b0 = *(bf16x8*)&sb2[offc + 4096 + rb0];
            b1 = *(bf16x8*)&sb2[offc + 4096 + rb0 + 512];
            b2 = *(bf16x8*)&sb2[offc + 4096 + rb0 + 1024];
            b3 = *(bf16x8*)&sb2[offc + 4096 + rb0 + 1536];
            asm volatile("s_waitcnt lgkmcnt(0)" ::: "memory");
            __builtin_amdgcn_sched_barrier(0);
            c00 = __builtin_amdgcn_mfma_f32_16x16x32_bf16(a0, b0, c00, 0, 0, 0);
            c01 = __builtin_amdgcn_mfma_f32_16x16x32_bf16(a0, b1, c01, 0, 0, 0);
            c02 = __builtin_amdgcn_mfma_f32_16x16x32_bf16(a0, b2, c02, 0, 0, 0);
            c03 = __builtin_amdgcn_mfma_f32_16x16x32_bf16(a0, b3, c03, 0, 0, 0);
            c10 = __builtin_amdgcn_mfma_f32_16x16x32_bf16(a1, b0, c10, 0, 0, 0);
            c11 = __builtin_amdgcn_mfma_f32_16x16x32_bf16(a1, b1, c11, 0, 0, 0);
            c12 = __builtin_amdgcn_mfma_f32_16x16x32_bf16(a1, b2, c12, 0, 0, 0);
            c13 = __builtin_amdgcn_mfma_f32_16x16x32_bf16(a1, b3, c13, 0, 0, 0);
        }
    }
    #undef STG2
    #undef KOF
    if (wlive){
        #pragma unroll
        for (int r = 0; r < 4; ++r){
            int orow0 = row0 + wm*32 + quad*4 + r;
            int oc = col0 + wn*64 + l15;
            if (orow0 < GM){
                if (oc      < NFFT) C[(size_t)orow0*NFFT + oc]      = c00[r];
                if (oc + 16 < NFFT) C[(size_t)orow0*NFFT + oc + 16] = c01[r];
                if (oc + 32 < NFFT) C[(size_t)orow0*NFFT + oc + 32] = c02[r];
                if (oc + 48 < NFFT) C[(size_t)orow0*NFFT + oc + 48] = c03[r];
            }
            if (orow0 + 16 < GM){
                if (oc      < NFFT) C[(size_t)(orow0+16)*NFFT + oc]      = c10[r];
                if (oc + 16 < NFFT) C[(size_t)(orow0+16)*NFFT + oc + 16] = c11[r];
                if (oc + 32 < NFFT) C[(size_t)(orow0+16)*NFFT + oc + 32] = c12[r];
                if (oc + 48 < NFFT) C[(size_t)(orow0+16)*NFFT + oc + 48] = c13[r];
            }
        }
    }
}

// ---------- overlap-add, float4: 4 outputs/thread (wsum==2 in cropped interior) ----------
__global__ __launch_bounds__(256) void k_ola(const float* __restrict__ frames, float* __restrict__ out){
    int gid = blockIdx.x*256 + threadIdx.x;
    if (gid >= 2*BB*(LL/4)) return;
    int o4 = (gid % (LL/4))*4;
    int rb = gid / (LL/4);                 // beam*BB + b
    int i  = o4 + HOP;                     // mult of 4; r in {0,4,...,156}
    int t1 = i / HOP;
    int r  = i - t1*HOP;
    const float4* fb = (const float4*)(frames + (size_t)rb*TT*NFFT);
    float4 a = fb[(t1*NFFT + r) >> 2];
    float4 b = fb[((t1-1)*NFFT + r + HOP) >> 2];
    ((float4*)out)[gid] = make_float4(0.5f*(a.x+b.x), 0.5f*(a.y+b.y), 0.5f*(a.z+b.z), 0.5f*(a.w+b.w));
}

extern "C" void kernel_launch(void* const* d_in, const int* in_sizes, int n_in,
                              void* d_out, int out_size, void* d_ws, size_t ws_size,
                              hipStream_t stream){
    const float* in  = (const float*)d_in[0];   // [B, L, C] fp32
    const float* win = (const float*)d_in[1];   // [320] fp32
    float* ws = (float*)d_ws;
    // ws (floats): mean 32 | invmax 8 | htab 2576 | pad -> header 3072
    //              | S1 (2,578,576) | S2 (2,578,576) | S (10,314,304)   total ~62 MB
    // aliases: part -> S1 head (dead before k_anorm); Ahi/Alo -> S1+S2 (dead after k_gstft);
    //          Bts + Bt -> head of d_out (dead until k_ola fully overwrites; NOT in S — R13 bug);
    //          A_ir -> S (post-scan); frames -> S1/S2 (post-pack)
    float* mean   = ws;
    float* invmax = ws + 32;
    float* htab   = ws + 48;
    float* S1     = ws + 3072;
    size_t nS1 = (size_t)2*BB*FB*TT;            // 2,578,576 floats
    float* S2 = S1 + nS1;
    float* S  = S2 + nS1;                       // 10,314,304 floats
    float* part = S1;
    short* Ahi = (short*)S1;                    // 8*4*160320 = 5,130,240 shorts
    short* Alo = Ahi + (size_t)BB*CC*NPAD;      // total 10,260,480 shorts <= S1+S2 (10,314,304 short-equiv)
    short* Bts = (short*)d_out;                 // 245,760 shorts (= 122,880 floats)
    short* Bt  = (short*)((float*)d_out + 131072); // 225,280 shorts at float-offset 131072 (16B aligned)
    short* A  = (short*)S;                      // irfft A: 16016*704 bf16
    float* frames = S1;                         // 16016*320 floats over dead S1+S2

    int ngen = 2*FB*CC + 384*640 + NFFT*LDK;    // fused table generation
    k_gen<<<dim3((ngen + 255)/256), dim3(256), 0, stream>>>(win, htab, Bts, Bt);
    k_stats1<<<dim3(BB*RBLK), dim3(256), 0, stream>>>(in, part);
    k_stats2<<<dim3(BB), dim3(128), 0, stream>>>(part, mean, invmax);
    k_anorm<<<dim3((BB*(NPAD/8) + 255)/256), dim3(256), 0, stream>>>(in, mean, invmax, Ahi, Alo);
    k_gstft<<<dim3(BB*TP*CC/128, 2), dim3(512), 0, stream>>>(Ahi, Alo, Bts, S);
    k_scan<<<dim3(BB*FB), dim3(512), 0, stream>>>(S, htab, S1, S2);
    k_pack<<<dim3(512), dim3(256), 0, stream>>>(S1, S2, A);
    k_gemm<<<dim3((GM + 127)/128, (NFFT + 127)/128), dim3(512), 0, stream>>>(A, Bt, frames);
    k_ola<<<dim3((2*BB*(LL/4) + 255)/256), dim3(256), 0, stream>>>(frames, (float*)d_out);
}

// Round 10
// 188.974 us; speedup vs baseline: 1.0107x; 1.0107x over previous
//
#include <hip/hip_runtime.h>
#include <hip/hip_bf16.h>
#include <math.h>

#define BB 8
#define LL 160000
#define CC 4
#define NFFT 320
#define HOP 160
#define FB 161          // rfft bins
#define TT 1001         // frames
#define TP 1024         // padded frames per batch (t-slots) for STFT GEMM
#define RBLK 128        // stats blocks per batch
#define PI_D 3.14159265358979323846
#define NPAD 160320     // reflect-padded samples per (b,c): p in [-160, 160159]

#define KWARM 4         // warm-up frames; tail weight 0.05^5 ~ 3e-7 rel << bf16 error floor (4.9e-4)

#define GM 16016        // irfft GEMM M = 2*BB*TT rows (beam,b,t)
#define KSEC 352        // irfft padded K per split-section (322 used)
#define LDK 704         // irfft A/Bt leading dim = 2 sections
#define KT 11           // irfft K-tiles of 32 per section
#define NGEN (2*FB*CC + 384*640 + NFFT*LDK)
// R23: (1) bf16-packed S1/S2: k_scan stores short4{hi-re,hi-im,lo-re,lo-im} (the
//      exact converts k_pack used to do -> bit-identical A); S1/S2 traffic halves,
//      pack loses ~5M VALU converts. (2) k_gemm grid transposed to (3,126): a row's
//      3 col-blocks dispatch adjacently -> A panel re-reads hit L2. (3) k_gen merged
//      into k_stats1 (independent DAG heads), block-ranged: -1 launch.
// R22: k_gstft 128x192, 2 blocks/CU, vmcnt(5) — NEUTRAL vs R21's 128x128 (phase-
//      economics model retired: k_gstft's ~42us bound is not barriers/tile/vmcnt).
// R21: k_gen exact mod-320 + f32 sincosf; MFMA issue must stay acc-rotating
//      (R20 regression: per-acc grouping = dependent chains stall matrix pipe).
// R20: k_scan full-strip 2 outputs/thread (-40% UPD); k_gemm 3-buffer ring.
// R19: anorm coalesced; scan direct stores + Q-form (scale-invariant solve).
// R14 lesson (direct-global gather, 47->115us): LDS staging is a latency-decoupling
// pipeline, not just a cache — do not remove it.
// LIFETIME NOTE (R13 bug): Bt/Bts must NOT live in the S region — k_gstft overwrites
// ALL of S. Both live in d_out's head (dead until k_ola fully overwrites at the end).

typedef __attribute__((ext_vector_type(8))) short bf16x8;
typedef __attribute__((ext_vector_type(4))) float f32x4;

__device__ __forceinline__ void ldsdma16(const short* g, short* l){
    // wave-level DMA: per-lane global src, wave-uniform LDS base + lane*16B
    __builtin_amdgcn_global_load_lds((const __attribute__((address_space(1))) void*)g,
                                     (__attribute__((address_space(3))) void*)l, 16, 0, 0);
}

__device__ __forceinline__ float2 cmulf(float2 a, float2 b){           // a*b
    return make_float2(a.x*b.x - a.y*b.y, a.x*b.y + a.y*b.x);
}
__device__ __forceinline__ float2 cmulcj(float2 a, float2 b){          // a*conj(b)
    return make_float2(a.x*b.x + a.y*b.y, a.y*b.x - a.x*b.y);
}
__device__ __forceinline__ float2 cjmul(float2 a, float2 b){           // conj(a)*b
    return make_float2(a.x*b.x + a.y*b.y, a.x*b.y - a.y*b.x);
}
__device__ __forceinline__ float2 csub(float2 a, float2 b){ return make_float2(a.x-b.x, a.y-b.y); }
__device__ __forceinline__ float2 cscale(float2 a, float s){ return make_float2(a.x*s, a.y*s); }
__device__ __forceinline__ float2 cdivf(float2 a, float2 b){           // a/b
    float inv = 1.0f/(b.x*b.x + b.y*b.y);
    return make_float2((a.x*b.x + a.y*b.y)*inv, (a.y*b.x - a.x*b.y)*inv);
}
__device__ __forceinline__ short bf_hi(float v){
    __hip_bfloat16 h = __float2bfloat16(v);
    short s; __builtin_memcpy(&s, &h, 2); return s;
}
__device__ __forceinline__ short bf_lo(float v){
    __hip_bfloat16 h = __float2bfloat16(v);
    float r = v - __bfloat162float(h);
    __hip_bfloat16 l = __float2bfloat16(r);
    short s; __builtin_memcpy(&s, &l, 2); return s;
}

// ---------- merged DAG heads: stats1 (blocks < BB*RBLK) | table gen (rest) ----------
__global__ __launch_bounds__(256) void k_genstats(const float* __restrict__ in, float* __restrict__ part,
        const float* __restrict__ win, float* __restrict__ htab,
        short* __restrict__ Bts, short* __restrict__ Bt){
    __shared__ float4 s4[256];
    __shared__ float4 mn4[256];
    __shared__ float4 mx4[256];
    int tid = threadIdx.x;
    if (blockIdx.x < BB*RBLK){
        // ----- stats1: per-(b,chunk) partial {sum4, min4, max4} -----
        int b = blockIdx.x / RBLK, chunk = blockIdx.x % RBLK;
        const float4* p = (const float4*)(in + (size_t)b*LL*CC);
        const int per = LL / RBLK;
        int start = chunk*per;
        float4 s  = make_float4(0.f,0.f,0.f,0.f);
        float4 mn = make_float4( 3.4e38f, 3.4e38f, 3.4e38f, 3.4e38f);
        float4 mx = make_float4(-3.4e38f,-3.4e38f,-3.4e38f,-3.4e38f);
        for (int i = start + tid; i < start + per; i += 256){
            float4 v = p[i];
            s.x += v.x; s.y += v.y; s.z += v.z; s.w += v.w;
            mn.x = fminf(mn.x, v.x); mn.y = fminf(mn.y, v.y); mn.z = fminf(mn.z, v.z); mn.w = fminf(mn.w, v.w);
            mx.x = fmaxf(mx.x, v.x); mx.y = fmaxf(mx.y, v.y); mx.z = fmaxf(mx.z, v.z); mx.w = fmaxf(mx.w, v.w);
        }
        s4[tid] = s; mn4[tid] = mn; mx4[tid] = mx;
        __syncthreads();
        for (int st = 128; st >= 1; st >>= 1){
            if (tid < st){
                float4 a = s4[tid], c = s4[tid+st];
                s4[tid] = make_float4(a.x+c.x, a.y+c.y, a.z+c.z, a.w+c.w);
                float4 d = mn4[tid], e = mn4[tid+st];
                mn4[tid] = make_float4(fminf(d.x,e.x), fminf(d.y,e.y), fminf(d.z,e.z), fminf(d.w,e.w));
                float4 f = mx4[tid], g = mx4[tid+st];
                mx4[tid] = make_float4(fmaxf(f.x,g.x), fmaxf(f.y,g.y), fmaxf(f.z,g.z), fmaxf(f.w,g.w));
            }
            __syncthreads();
        }
        if (tid == 0){
            float* dst = part + (size_t)(b*RBLK + chunk)*12;
            float4 a = s4[0], d = mn4[0], f = mx4[0];
            dst[0]=a.x; dst[1]=a.y; dst[2]=a.z; dst[3]=a.w;
            dst[4]=d.x; dst[5]=d.y; dst[6]=d.z; dst[7]=d.w;
            dst[8]=f.x; dst[9]=f.y; dst[10]=f.z; dst[11]=f.w;
        }
        return;
    }
    // ----- table generation (R21: exact mod-320 + f32 sincosf for big tables) -----
    int gid = (blockIdx.x - BB*RBLK)*256 + tid;
    const float W0 = (float)(2.0*PI_D/320.0);
    if (gid < 2*FB*CC){
        int i = gid;
        int c = i & 3;
        int k = (i >> 2) % FB;
        int m = i / (FB*CC);
        double coef = 2.0*PI_D*50.0*0.027*sin(40.0*PI_D/180.0)/340.0;
        double sgn = (m == 0) ? -1.0 : 1.0;
        double ph = sgn*coef*(double)k*(double)c;
        double s, c2;
        sincos(ph, &s, &c2);
        ((float2*)htab)[i] = make_float2((float)c2, (float)s);
        return;
    }
    gid -= 2*FB*CC;
    if (gid < 384*640){
        int col = gid / 640, kk = gid % 640;
        int n = (kk >= 320) ? kk - 320 : kk;
        int sec = (kk >= 320) ? 1 : 0;
        float v = 0.f;
        if (col < 2*FB){
            int k = col >> 1;
            int mr = (k*n) % 320;                    // exact reduction
            float s, co; sincosf(W0*(float)mr, &s, &co);
            v = win[n] * ((col & 1) ? -s : co);
        }
        Bts[gid] = sec ? bf_lo(v) : bf_hi(v);
        return;
    }
    gid -= 384*640;
    if (gid < NFFT*LDK){
        int n = gid / LDK, kk = gid % LDK;
        int sec = (kk >= KSEC) ? 1 : 0;
        int kk2 = kk - (sec ? KSEC : 0);
        float v = 0.f;
        if (kk2 < 2*FB){
            int bin = kk2 >> 1;
            float c = ((bin == 0 || bin == 160) ? 1.0f : 2.0f) * (1.0f/320.0f);
            int mr = (bin*n) % 320;                  // exact reduction
            float s, co; sincosf(W0*(float)mr, &s, &co);
            v = (kk2 & 1) ? -c*s : c*co;
        }
        Bt[(size_t)n*LDK + kk] = sec ? bf_lo(v) : bf_hi(v);
    }
}

// ---------- stage 2: finalize mean + invmax per batch ----------
__global__ __launch_bounds__(128) void k_stats2(const float* __restrict__ part,
                                                float* __restrict__ mean, float* __restrict__ invmax){
    __shared__ float4 s4[128];
    __shared__ float4 mn4[128];
    __shared__ float4 mx4[128];
    int b = blockIdx.x, tid = threadIdx.x;
    const float* src = part + (size_t)(b*RBLK + tid)*12;
    s4[tid]  = make_float4(src[0], src[1], src[2], src[3]);
    mn4[tid] = make_float4(src[4], src[5], src[6], src[7]);
    mx4[tid] = make_float4(src[8], src[9], src[10], src[11]);
    __syncthreads();
    for (int st = 64; st >= 1; st >>= 1){
        if (tid < st){
            float4 a = s4[tid], c = s4[tid+st];
            s4[tid] = make_float4(a.x+c.x, a.y+c.y, a.z+c.z, a.w+c.w);
            float4 d = mn4[tid], e = mn4[tid+st];
            mn4[tid] = make_float4(fminf(d.x,e.x), fminf(d.y,e.y), fminf(d.z,e.z), fminf(d.w,e.w));
            float4 f = mx4[tid], g = mx4[tid+st];
            mx4[tid] = make_float4(fmaxf(f.x,g.x), fmaxf(f.y,g.y), fmaxf(f.z,g.z), fmaxf(f.w,g.w));
        }
        __syncthreads();
    }
    if (tid == 0){
        float4 sum = s4[0], mn = mn4[0], mx = mx4[0];
        float m0 = sum.x*(1.0f/LL), m1 = sum.y*(1.0f/LL), m2 = sum.z*(1.0f/LL), m3 = sum.w*(1.0f/LL);
        mean[b*4+0]=m0; mean[b*4+1]=m1; mean[b*4+2]=m2; mean[b*4+3]=m3;
        float a0 = fmaxf(mx.x - m0, m0 - mn.x);
        float a1 = fmaxf(mx.y - m1, m1 - mn.y);
        float a2 = fmaxf(mx.z - m2, m2 - mn.z);
        float a3 = fmaxf(mx.w - m3, m3 - mn.w);
        invmax[b] = 1.0f / fmaxf(fmaxf(a0, a1), fmaxf(a2, a3));
    }
}

// ---------- A-normalize (R19): coalesced — thread = 8 consecutive samples x 4 channels ----------
__global__ __launch_bounds__(256) void k_anorm(const float* __restrict__ in,
        const float* __restrict__ mean, const float* __restrict__ invmax,
        short* __restrict__ Ahi, short* __restrict__ Alo){
    int gid = blockIdx.x*256 + threadIdx.x;
    if (gid >= BB*(NPAD/8)) return;
    int p8 = gid % (NPAD/8);
    int b  = gid / (NPAD/8);
    float4 mc = *(const float4*)&mean[b*4];
    float iv = invmax[b];
    const float4* px = (const float4*)(in + (size_t)b*LL*CC);   // [LL][4ch]
    bf16x8 h0{}, h1{}, h2{}, h3{}, l0{}, l1{}, l2{}, l3{};
    #pragma unroll
    for (int j = 0; j < 8; ++j){
        int p = p8*8 + j - 160;
        int m2 = p < 0 ? -p : (p >= LL ? 2*LL - 2 - p : p);
        float4 v = px[m2];
        float v0 = (v.x - mc.x)*iv, v1 = (v.y - mc.y)*iv;
        float v2 = (v.z - mc.z)*iv, v3 = (v.w - mc.w)*iv;
        h0[j] = bf_hi(v0); l0[j] = bf_lo(v0);
        h1[j] = bf_hi(v1); l1[j] = bf_lo(v1);
        h2[j] = bf_hi(v2); l2[j] = bf_lo(v2);
        h3[j] = bf_hi(v3); l3[j] = bf_lo(v3);
    }
    size_t o = (size_t)(b*4)*NPAD + (size_t)p8*8;
    *(bf16x8*)&Ahi[o]          = h0;  *(bf16x8*)&Alo[o]          = l0;
    *(bf16x8*)&Ahi[o +   NPAD] = h1;  *(bf16x8*)&Alo[o +   NPAD] = l1;
    *(bf16x8*)&Ahi[o + 2*NPAD] = h2;  *(bf16x8*)&Alo[o + 2*NPAD] = l2;
    *(bf16x8*)&Ahi[o + 3*NPAD] = h3;  *(bf16x8*)&Alo[o + 3*NPAD] = l3;
}

// ---------- STFT as MFMA GEMM (R22): 128x192 tile, 8 waves (4x2; 32x96/wave) ----------
// S out layout: complex S[b][k][h][t] (h = channel-pair), float4 per (b,k,h,t)
__global__ __launch_bounds__(512, 4) void k_gstft(const short* __restrict__ Ahi, const short* __restrict__ Alo,
        const short* __restrict__ Bts, float* __restrict__ S){
    __shared__ short stage[40960];           // 80 KB: 2 buffers x 20480 shorts
    int tid = threadIdx.x;
    int row0 = blockIdx.x*128;               // over b*TP*CC rows
    int col0 = blockIdx.y*192;               // 2 col-blocks cover 384 >= 322
    int b  = row0 >> 12;                     // TP*CC = 4096 rows per batch
    int t0 = (row0 & 4095) >> 2;             // in {0,32,...,992} — always < TT
    int wave = tid >> 6, lane = tid & 63;
    int wm = wave >> 1, wn = wave & 1;       // 4x2 wave grid: 32 rows x 96 cols each
    int l15 = lane & 15, quad = lane >> 4;
    // ---- staging: 5 flat-slot DMAs per thread; chunk = (tid&3)^((tid>>3)&3) ----
    int chunk = (tid & 3) ^ ((tid >> 3) & 3);
    int tq4 = tid >> 2;
    int rowA = tq4;                          // A rows 0..127, channel = row&3
    int tls = t0 + (rowA >> 2); if (tls >= TT) tls = TT - 1;
    size_t gao = (size_t)(b*4 + (rowA & 3))*NPAD + (size_t)tls*160 + chunk*8;
    const short* src0 = Ahi + gao;
    const short* src1 = Alo + gao;
    const short* src2 = Bts + (size_t)(col0 + tq4)*640 + chunk*8;
    const short* src3 = (tid < 256)
        ? Bts + (size_t)(col0 + 128 + tq4)*640 + chunk*8
        : Bts + (size_t)(col0 + ((tid - 256) >> 2))*640 + 320 + chunk*8;
    const short* src4 = Bts + (size_t)(col0 + 64 + tq4)*640 + 320 + chunk*8;
    short* lw = stage + wave*512;            // + j*4096 + buffer offset
    // ---- read addresses (swizzle (row>>1)&3 == (l15>>1)&3 for all row patterns) ----
    int sw  = (l15 >> 1) & 3;
    int c0r = (quad ^ sw) * 8;
    int ra0 = (wm*32 + l15)*32 + c0r;        // A frag 0; frag 1 at +512; Al at +4096
    int rbB = (wn*96 + l15)*32 + c0r;        // B frag j at +8192 (hi) / +14336 (lo) + j*512
    f32x4 c00 = {0.f,0.f,0.f,0.f}, c01 = c00, c02 = c00, c03 = c00, c04 = c00, c05 = c00;
    f32x4 c10 = c00, c11 = c00, c12 = c00, c13 = c00, c14 = c00, c15 = c00;

    #define STG(kt_, off_) do{ int ko_ = (kt_)*32; \
        ldsdma16(src0 + ko_, lw + (off_));          \
        ldsdma16(src1 + ko_, lw + (off_) + 4096);   \
        ldsdma16(src2 + ko_, lw + (off_) + 8192);   \
        ldsdma16(src3 + ko_, lw + (off_) + 12288);  \
        ldsdma16(src4 + ko_, lw + (off_) + 16384);  \
    }while(0)

    STG(0, 0);                               // 2-deep prologue
    STG(1, 20480);
    #pragma unroll
    for (int kt = 0; kt < 10; ++kt){
        int offc = (kt & 1) ? 20480 : 0;
        if (kt < 9) asm volatile("s_waitcnt vmcnt(5)" ::: "memory");
        else        asm volatile("s_waitcnt vmcnt(0)" ::: "memory");
        __builtin_amdgcn_s_barrier();        // buf[kt&1] ready
        bf16x8 a0h = *(bf16x8*)&stage[offc + ra0];
        bf16x8 a1h = *(bf16x8*)&stage[offc + ra0 + 512];
        bf16x8 a0l = *(bf16x8*)&stage[offc + 4096 + ra0];
        bf16x8 a1l = *(bf16x8*)&stage[offc + 4096 + ra0 + 512];
        bf16x8 b0h = *(bf16x8*)&stage[offc + 8192 + rbB];
        bf16x8 b1h = *(bf16x8*)&stage[offc + 8192 + rbB + 512];
        bf16x8 b2h = *(bf16x8*)&stage[offc + 8192 + rbB + 1024];
        bf16x8 b3h = *(bf16x8*)&stage[offc + 8192 + rbB + 1536];
        bf16x8 b4h = *(bf16x8*)&stage[offc + 8192 + rbB + 2048];
        bf16x8 b5h = *(bf16x8*)&stage[offc + 8192 + rbB + 2560];
        // group1: hh + lh, acc-rotating
        c00 = __builtin_amdgcn_mfma_f32_16x16x32_bf16(a0h, b0h, c00, 0, 0, 0);
        c01 = __builtin_amdgcn_mfma_f32_16x16x32_bf16(a0h, b1h, c01, 0, 0, 0);
        c02 = __builtin_amdgcn_mfma_f32_16x16x32_bf16(a0h, b2h, c02, 0, 0, 0);
        c03 = __builtin_amdgcn_mfma_f32_16x16x32_bf16(a0h, b3h, c03, 0, 0, 0);
        c04 = __builtin_amdgcn_mfma_f32_16x16x32_bf16(a0h, b4h, c04, 0, 0, 0);
        c05 = __builtin_amdgcn_mfma_f32_16x16x32_bf16(a0h, b5h, c05, 0, 0, 0);
        c10 = __builtin_amdgcn_mfma_f32_16x16x32_bf16(a1h, b0h, c10, 0, 0, 0);
        c11 = __builtin_amdgcn_mfma_f32_16x16x32_bf16(a1h, b1h, c11, 0, 0, 0);
        c12 = __builtin_amdgcn_mfma_f32_16x16x32_bf16(a1h, b2h, c12, 0, 0, 0);
        c13 = __builtin_amdgcn_mfma_f32_16x16x32_bf16(a1h, b3h, c13, 0, 0, 0);
        c14 = __builtin_amdgcn_mfma_f32_16x16x32_bf16(a1h, b4h, c14, 0, 0, 0);
        c15 = __builtin_amdgcn_mfma_f32_16x16x32_bf16(a1h, b5h, c15, 0, 0, 0);
        c00 = __builtin_amdgcn_mfma_f32_16x16x32_bf16(a0l, b0h, c00, 0, 0, 0);
        c01 = __builtin_amdgcn_mfma_f32_16x16x32_bf16(a0l, b1h, c01, 0, 0, 0);
        c02 = __builtin_amdgcn_mfma_f32_16x16x32_bf16(a0l, b2h, c02, 0, 0, 0);
        c03 = __builtin_amdgcn_mfma_f32_16x16x32_bf16(a0l, b3h, c03, 0, 0, 0);
        c04 = __builtin_amdgcn_mfma_f32_16x16x32_bf16(a0l, b4h, c04, 0, 0, 0);
        c05 = __builtin_amdgcn_mfma_f32_16x16x32_bf16(a0l, b5h, c05, 0, 0, 0);
        c10 = __builtin_amdgcn_mfma_f32_16x16x32_bf16(a1l, b0h, c10, 0, 0, 0);
        c11 = __builtin_amdgcn_mfma_f32_16x16x32_bf16(a1l, b1h, c11, 0, 0, 0);
        c12 = __builtin_amdgcn_mfma_f32_16x16x32_bf16(a1l, b2h, c12, 0, 0, 0);
        c13 = __builtin_amdgcn_mfma_f32_16x16x32_bf16(a1l, b3h, c13, 0, 0, 0);
        c14 = __builtin_amdgcn_mfma_f32_16x16x32_bf16(a1l, b4h, c14, 0, 0, 0);
        c15 = __builtin_amdgcn_mfma_f32_16x16x32_bf16(a1l, b5h, c15, 0, 0, 0);
        // Bl reads (Bh registers die above)
        bf16x8 b0l = *(bf16x8*)&stage[offc + 14336 + rbB];
        bf16x8 b1l = *(bf16x8*)&stage[offc + 14336 + rbB + 512];
        bf16x8 b2l = *(bf16x8*)&stage[offc + 14336 + rbB + 1024];
        bf16x8 b3l = *(bf16x8*)&stage[offc + 14336 + rbB + 1536];
        bf16x8 b4l = *(bf16x8*)&stage[offc + 14336 + rbB + 2048];
        bf16x8 b5l = *(bf16x8*)&stage[offc + 14336 + rbB + 2560];
        asm volatile("s_waitcnt lgkmcnt(0)" ::: "memory");
        __builtin_amdgcn_sched_barrier(0);   // rule #18: pin ALL buffer reads before reuse barrier
        __builtin_amdgcn_s_barrier();        // all waves done reading buf[kt&1]
        if (kt < 8) STG(kt+2, offc);         // overwrite just-freed buffer
        // group2: hl
        c00 = __builtin_amdgcn_mfma_f32_16x16x32_bf16(a0h, b0l, c00, 0, 0, 0);
        c01 = __builtin_amdgcn_mfma_f32_16x16x32_bf16(a0h, b1l, c01, 0, 0, 0);
        c02 = __builtin_amdgcn_mfma_f32_16x16x32_bf16(a0h, b2l, c02, 0, 0, 0);
        c03 = __builtin_amdgcn_mfma_f32_16x16x32_bf16(a0h, b3l, c03, 0, 0, 0);
        c04 = __builtin_amdgcn_mfma_f32_16x16x32_bf16(a0h, b4l, c04, 0, 0, 0);
        c05 = __builtin_amdgcn_mfma_f32_16x16x32_bf16(a0h, b5l, c05, 0, 0, 0);
        c10 = __builtin_amdgcn_mfma_f32_16x16x32_bf16(a1h, b0l, c10, 0, 0, 0);
        c11 = __builtin_amdgcn_mfma_f32_16x16x32_bf16(a1h, b1l, c11, 0, 0, 0);
        c12 = __builtin_amdgcn_mfma_f32_16x16x32_bf16(a1h, b2l, c12, 0, 0, 0);
        c13 = __builtin_amdgcn_mfma_f32_16x16x32_bf16(a1h, b3l, c13, 0, 0, 0);
        c14 = __builtin_amdgcn_mfma_f32_16x16x32_bf16(a1h, b4l, c14, 0, 0, 0);
        c15 = __builtin_amdgcn_mfma_f32_16x16x32_bf16(a1h, b5l, c15, 0, 0, 0);
    }
    #undef STG
    // ---- epilogue: shfl-pair assembly, direct global store (no LDS) ----
    int tq  = t0 + wm*8 + quad;
    int kgb = (col0 >> 1) + wn*48 + (l15 >> 1);
    int h   = l15 & 1;
    float4* S4 = (float4*)S;
    #define EPI(cf, i_, j_) do{ \
        int t = tq + 4*(i_); \
        int kg = kgb + 8*(j_); \
        if (t < TT && kg < FB){ \
            float p0 = __shfl_xor(cf[0], 1); \
            float p1 = __shfl_xor(cf[1], 1); \
            float p2 = __shfl_xor(cf[2], 1); \
            float p3 = __shfl_xor(cf[3], 1); \
            float4 v = h ? make_float4(p2, cf[2], p3, cf[3]) \
                         : make_float4(cf[0], p0, cf[1], p1); \
            S4[((size_t)((b*FB + kg)*2 + h))*TT + t] = v; \
        } \
    }while(0)
    EPI(c00, 0, 0); EPI(c01, 0, 1); EPI(c02, 0, 2); EPI(c03, 0, 3); EPI(c04, 0, 4); EPI(c05, 0, 5);
    EPI(c10, 1, 0); EPI(c11, 1, 1); EPI(c12, 1, 2); EPI(c13, 1, 3); EPI(c14, 1, 4); EPI(c15, 1, 5);
    #undef EPI
}

// covariance recurrence, original weighted form (first-frame handling): R = a*R + wg*outer(X)
#define UPD(first) do{ \
    float aa = (first) ? 0.f : 0.05f; float wg = (first) ? 1.f : 0.95f; \
    float y0x=wg*x0.x, y0y=wg*x0.y, y1x=wg*x1.x, y1y=wg*x1.y; \
    float y2x=wg*x2.x, y2y=wg*x2.y, y3x=wg*x3.x, y3y=wg*x3.y; \
    d0 = aa*d0 + y0x*x0.x + y0y*x0.y; \
    d1 = aa*d1 + y1x*x1.x + y1y*x1.y; \
    d2 = aa*d2 + y2x*x2.x + y2y*x2.y; \
    d3 = aa*d3 + y3x*x3.x + y3y*x3.y; \
    r10.x = aa*r10.x + y1x*x0.x + y1y*x0.y;  r10.y = aa*r10.y + y1y*x0.x - y1x*x0.y; \
    r20.x = aa*r20.x + y2x*x0.x + y2y*x0.y;  r20.y = aa*r20.y + y2y*x0.x - y2x*x0.y; \
    r30.x = aa*r30.x + y3x*x0.x + y3y*x0.y;  r30.y = aa*r30.y + y3y*x0.x - y3x*x0.y; \
    r21.x = aa*r21.x + y2x*x1.x + y2y*x1.y;  r21.y = aa*r21.y + y2y*x1.x - y2x*x1.y; \
    r31.x = aa*r31.x + y3x*x1.x + y3y*x1.y;  r31.y = aa*r31.y + y3y*x1.x - y3x*x1.y; \
    r32.x = aa*r32.x + y3x*x2.x + y3y*x2.y;  r32.y = aa*r32.y + y3y*x2.x - y3x*x2.y; \
}while(0)

// Q-form (R19): Q = 0.05*Q + outer(X); Q = R/0.95 exactly when no first-frame is in
// the truncated window. The solve is scale-invariant in R -> outputs identical.
#define UPDQ do{ \
    d0 = 0.05f*d0 + x0.x*x0.x + x0.y*x0.y; \
    d1 = 0.05f*d1 + x1.x*x1.x + x1.y*x1.y; \
    d2 = 0.05f*d2 + x2.x*x2.x + x2.y*x2.y; \
    d3 = 0.05f*d3 + x3.x*x3.x + x3.y*x3.y; \
    r10.x = 0.05f*r10.x + x1.x*x0.x + x1.y*x0.y;  r10.y = 0.05f*r10.y + x1.y*x0.x - x1.x*x0.y; \
    r20.x = 0.05f*r20.x + x2.x*x0.x + x2.y*x0.y;  r20.y = 0.05f*r20.y + x2.y*x0.x - x2.x*x0.y; \
    r30.x = 0.05f*r30.x + x3.x*x0.x + x3.y*x0.y;  r30.y = 0.05f*r30.y + x3.y*x0.x - x3.x*x0.y; \
    r21.x = 0.05f*r21.x + x2.x*x1.x + x2.y*x1.y;  r21.y = 0.05f*r21.y + x2.y*x1.x - x2.x*x1.y; \
    r31.x = 0.05f*r31.x + x3.x*x1.x + x3.y*x1.y;  r31.y = 0.05f*r31.y + x3.y*x1.x - x3.x*x1.y; \
    r32.x = 0.05f*r32.x + x3.x*x2.x + x3.y*x2.y;  r32.y = 0.05f*r32.y + x3.y*x2.x - x3.x*x2.y; \
}while(0)

// ---------- scan (R20 + R23): full-strip, 2 outputs/thread, bf16-packed output ----------
// S1/S2 now hold short4{hi-re, hi-im, lo-re, lo-im} per (bf,t) — the exact converts
// k_pack used to perform (bit-identical A), at half the traffic.
__global__ __launch_bounds__(512) void k_scan(const float* __restrict__ S, const float* __restrict__ htab,
                      short* __restrict__ S1, short* __restrict__ S2){
    __shared__ float4 tile[2016];     // swizzled full strip (2*TT=2002 used; swz stays in-group)
    int bf = blockIdx.x;              // b*FB + f
    int f  = bf % FB;
    int tid = threadIdx.x;
    const float4* P0 = (const float4*)S + (size_t)(bf*2)*TT;
    const float4* P1 = P0 + TT;
    for (int i = tid; i < 2*TT; i += 512){
        int tt = i >> 1;
        tile[i ^ ((i>>4)&7)] = (i & 1) ? P1[tt] : P0[tt];   // interleave planes into tile
    }
    __syncthreads();
    int t0 = tid*2;
    if (t0 < TT){
        const float2* hp = (const float2*)htab;
        float2 ha0 = hp[f*4+0], ha1 = hp[f*4+1], ha2 = hp[f*4+2], ha3 = hp[f*4+3];
        float2 hb0 = hp[(FB+f)*4+0], hb1 = hp[(FB+f)*4+1], hb2 = hp[(FB+f)*4+2], hb3 = hp[(FB+f)*4+3];
        float d0=0,d1=0,d2=0,d3=0;
        float2 r10={0,0}, r20={0,0}, r30={0,0}, r21={0,0}, r31={0,0}, r32={0,0};
        float2 x0, x1, x2, x3;
        #define LOADX(tau_) do{ int i0_ = 2*(tau_); \
            float4 v0_ = tile[i0_ ^ ((i0_>>4)&7)]; \
            float4 v1_ = tile[(i0_+1) ^ (((i0_+1)>>4)&7)]; \
            x0 = make_float2(v0_.x, v0_.y); x1 = make_float2(v0_.z, v0_.w); \
            x2 = make_float2(v1_.x, v1_.y); x3 = make_float2(v1_.z, v1_.w); \
        }while(0)
        bool qform = (t0 >= KWARM + 1);   // no frame-0 special in any window
        int ts = t0 - KWARM; if (ts < 0) ts = 0;
        if (qform){
            #pragma unroll
            for (int u = 0; u < KWARM; ++u){ LOADX(ts + u); UPDQ; }
        } else {
            for (int tau = 0; tau < t0; ++tau){ LOADX(tau); UPD(tau == 0); }
        }
        short4* S1g = (short4*)S1 + (size_t)bf*TT;
        short4* S2g = (short4*)S2 + (size_t)bf*TT;
        #pragma unroll
        for (int j = 0; j < 2; ++j){
            int t = t0 + j;
            if (t >= TT) break;
            LOADX(t);
            if (qform) UPDQ; else UPD(t == 0);
            float trc = d0 + d1 + d2 + d3;
            float lam = trc * 0.25f;
            float e0 = d0 + lam, e1 = d1 + lam, e2 = d2 + lam, e3 = d3 + lam;
            float detP = e0*e1 - (r10.x*r10.x + r10.y*r10.y);
            float2 w00 = csub(cscale(r20, e1), cmulf(r10, r21));
            float2 w01 = csub(cscale(r30, e1), cmulf(r10, r31));
            float2 w10 = csub(cscale(r21, e0), cjmul(r10, r20));
            float2 w11 = csub(cscale(r31, e0), cjmul(r10, r30));
            float2 va = cjmul(r30, w00), vb = cjmul(r31, w10);
            float2 V10 = make_float2(va.x + vb.x, -(va.y + vb.y));
            float reV00 = r20.x*w00.x + r20.y*w00.y + r21.x*w10.x + r21.y*w10.y;
            float reV11 = r30.x*w01.x + r30.y*w01.y + r31.x*w11.x + r31.y*w11.y;
            float t00 = detP*e2 - reV00;
            float t11 = detP*e3 - reV11;
            float2 t10 = csub(cscale(r32, detP), V10);
            float detT = t00*t11 - (t10.x*t10.x + t10.y*t10.y);
            #pragma unroll
            for (int m = 0; m < 2; ++m){
                float2 h0 = m ? hb0 : ha0;
                float2 h1 = m ? hb1 : ha1;
                float2 h2 = m ? hb2 : ha2;
                float2 h3 = m ? hb3 : ha3;
                float2 g0 = csub(cscale(h0, e1), cjmul(r10, h1));
                float2 g1 = csub(cscale(h1, e0), cmulf(r10, h0));
                float2 ta = cmulf(r20, g0), tb = cmulf(r21, g1);
                float2 hh0 = make_float2(detP*h2.x - ta.x - tb.x, detP*h2.y - ta.y - tb.y);
                ta = cmulf(r30, g0); tb = cmulf(r31, g1);
                float2 hh1 = make_float2(detP*h3.x - ta.x - tb.x, detP*h3.y - ta.y - tb.y);
                float2 y20 = csub(cscale(hh0, t11), cjmul(t10, hh1));
                float2 y21 = csub(cscale(hh1, t00), cmulf(t10, hh0));
                float2 u20 = cscale(y20, detP), u21 = cscale(y21, detP);
                ta = cmulcj(y20, r20); tb = cmulcj(y21, r30);
                float2 q0 = make_float2(detT*h0.x - ta.x - tb.x, detT*h0.y - ta.y - tb.y);
                ta = cmulcj(y20, r21); tb = cmulcj(y21, r31);
                float2 q1 = make_float2(detT*h1.x - ta.x - tb.x, detT*h1.y - ta.y - tb.y);
                float2 u10 = csub(cscale(q0, e1), cjmul(r10, q1));
                float2 u11 = csub(cscale(q1, e0), cmulf(r10, q0));
                float2 den = cjmul(h0, u10), tmp;
                tmp = cjmul(h1, u11); den.x += tmp.x; den.y += tmp.y;
                tmp = cjmul(h2, u20); den.x += tmp.x; den.y += tmp.y;
                tmp = cjmul(h3, u21); den.x += tmp.x; den.y += tmp.y;
                float2 num = cjmul(u10, x0);
                tmp = cjmul(u11, x1); num.x += tmp.x; num.y += tmp.y;
                tmp = cjmul(u20, x2); num.x += tmp.x; num.y += tmp.y;
                tmp = cjmul(u21, x3); num.x += tmp.x; num.y += tmp.y;
                float2 s = cdivf(num, make_float2(den.x, -den.y));
                short4 pk;
                pk.x = bf_hi(s.x); pk.y = bf_hi(s.y);
                pk.z = bf_lo(s.x); pk.w = bf_lo(s.y);
                if (m) S2g[t] = pk; else S1g[t] = pk;
            }
        }
        #undef LOADX
    }
}

// ---------- pack (R23): pure transpose of bf16-packed S1/S2 into irfft A ----------
__global__ __launch_bounds__(256) void k_pack(const short* __restrict__ S1, const short* __restrict__ S2,
                                              short* __restrict__ A){
    __shared__ short tile[32*708];        // 45,312 B; row = t-in-tile, col = kk (hi 0..351 | lo 352..703)
    int bid = blockIdx.x;                 // rb*32 + tb
    int tb = bid & 31, rb = bid >> 5;
    int t0 = tb*32;
    int beam = rb >> 3, b = rb & 7;
    const short4* Sp = (const short4*)(beam ? S2 : S1) + (size_t)b*FB*TT;
    int tid = threadIdx.x;
    for (int idx = tid; idx < 32*176; idx += 256){
        int bin = idx >> 5, tq = idx & 31;
        int t = t0 + tq;
        short4 s = make_short4(0, 0, 0, 0);
        if (bin < FB && t < TT) s = Sp[(size_t)bin*TT + t];
        int c0 = 2*bin;
        tile[tq*708 + c0]            = s.x;
        tile[tq*708 + c0 + 1]        = s.y;
        tile[tq*708 + KSEC + c0]     = s.z;
        tile[tq*708 + KSEC + c0 + 1] = s.w;
    }
    __syncthreads();
    for (int idx = tid; idx < 32*176; idx += 256){
        int tq = idx / 176, k4 = idx % 176;
        int t = t0 + tq;
        if (t < TT)
            *(short4*)&A[(size_t)(rb*TT + t)*LDK + k4*4] = *(short4*)&tile[tq*708 + k4*4];
    }
}

// ---------- irfft MFMA GEMM (R20 + R23): 3-buffer ring; grid transposed (3,126) ----------
// blockIdx.x = col (3), blockIdx.y = row (126): a row's col-blocks dispatch
// adjacently -> the 2nd/3rd reads of each 176KB A panel hit L2.
__global__ __launch_bounds__(512, 4) void k_gemm(const short* __restrict__ A, const short* __restrict__ Bt,
                                                 float* __restrict__ C){
    __shared__ short sb2[24576];           // 48 KB: 3 buffers x (A|B) x 4096 shorts
    int tid = threadIdx.x;
    int row0 = blockIdx.y * 128;
    int col0 = blockIdx.x * 128;
    int wave = tid >> 6, lane = tid & 63;
    int wm = wave >> 1, wn = wave & 1;     // 4x2 wave grid: 32 rows x 64 cols each
    int l15 = lane & 15, quad = lane >> 4;
    bool wlive = (col0 + wn*64) < NFFT;    // x=2,wn=1 waves are fully past NFFT
    // staging (per lane)
    int rowS  = wave*16 + (lane >> 2);
    int chunk = (lane & 3) ^ ((lane >> 3) & 3);
    int grS = row0 + rowS; if (grS >= GM) grS = GM - 1;       // clamp; stores guarded
    int grB = col0 + rowS; if (grB >= NFFT) grB = NFFT - 1;   // clamp; cols >=320 unused
    const short* gA = A  + (size_t)grS*LDK + chunk*8;
    const short* gB = Bt + (size_t)grB*LDK + chunk*8;
    short* lA = sb2 + wave*512;
    // reads
    int sw  = (l15 >> 1) & 3;
    int c0r = (quad ^ sw) * 8;
    int ra0 = (wm*32 + l15)*32 + c0r;      // frag 1 at +512
    int rb0 = (wn*64 + l15)*32 + c0r;      // frag j at +j*512
    f32x4 c00 = {0.f,0.f,0.f,0.f}, c01 = c00, c02 = c00, c03 = c00;
    f32x4 c10 = c00, c11 = c00, c12 = c00, c13 = c00;

    #define KOF(s_, ka_, kb_) { int sg_ = ((s_) >= 22) ? 2 : ((s_) >= 11) ? 1 : 0; \
        int kt_ = (s_) - sg_*11; \
        ka_ = ((sg_ == 1) ? KSEC : 0) + kt_*32; \
        kb_ = ((sg_ == 2) ? KSEC : 0) + kt_*32; }
    #define STG2(s_, off_) do{ int ka_, kb_; KOF(s_, ka_, kb_); \
        ldsdma16(gA + ka_, lA + (off_));        \
        ldsdma16(gB + kb_, lA + (off_) + 4096); \
    }while(0)

    STG2(0, 0);                            // 2-deep prologue into ring slots 0,1
    STG2(1, 8192);
    #pragma unroll
    for (int s = 0; s < 33; ++s){
        int offc = (s % 3) * 8192;
        if (s < 32) asm volatile("s_waitcnt vmcnt(2)" ::: "memory");
        else        asm volatile("s_waitcnt vmcnt(0)" ::: "memory");
        __builtin_amdgcn_s_barrier();      // buf[s%3] ready; also: all s-1 reads done
        if (s < 31) STG2(s+2, ((s+2) % 3) * 8192);   // writes buf[(s-1)%3] — freed above
        bf16x8 a0{}, a1{}, b0{}, b1{}, b2{}, b3{};
        if (wlive){
            a0 = *(bf16x8*)&sb2[offc + ra0];
            a1 = *(bf16x8*)&sb2[offc + ra0 + 512];
            b0 = *(bf16x8*)&sb2[offc + 4096 + rb0];
            b1 = *(bf16x8*)&sb2[offc + 4096 + rb0 + 512];
            b2 = *(bf16x8*)&sb2[offc + 4096 + rb0 + 1024];
            b3 = *(bf16x8*)&sb2[offc + 4096 + rb0 + 1536];
            asm volatile("s_waitcnt lgkmcnt(0)" ::: "memory");
            __builtin_amdgcn_sched_barrier(0);
            c00 = __builtin_amdgcn_mfma_f32_16x16x32_bf16(a0, b0, c00, 0, 0, 0);
            c01 = __builtin_amdgcn_mfma_f32_16x16x32_bf16(a0, b1, c01, 0, 0, 0);
            c02 = __builtin_amdgcn_mfma_f32_16x16x32_bf16(a0, b2, c02, 0, 0, 0);
            c03 = __builtin_amdgcn_mfma_f32_16x16x32_bf16(a0, b3, c03, 0, 0, 0);
            c10 = __builtin_amdgcn_mfma_f32_16x16x32_bf16(a1, b0, c10, 0, 0, 0);
            c11 = __builtin_amdgcn_mfma_f32_16x16x32_bf16(a1, b1, c11, 0, 0, 0);
            c12 = __builtin_amdgcn_mfma_f32_16x16x32_bf16(a1, b2, c12, 0, 0, 0);
            c13 = __builtin_amdgcn_mfma_f32_16x16x32_bf16(a1, b3, c13, 0, 0, 0);
        }
    }
    #undef STG2
    #undef KOF
    if (wlive){
        #pragma unroll
        for (int r = 0; r < 4; ++r){
            int orow0 = row0 + wm*32 + quad*4 + r;
            int oc = col0 + wn*64 + l15;
            if (orow0 < GM){
                if (oc      < NFFT) C[(size_t)orow0*NFFT + oc]      = c00[r];
                if (oc + 16 < NFFT) C[(size_t)orow0*NFFT + oc + 16] = c01[r];
                if (oc + 32 < NFFT) C[(size_t)orow0*NFFT + oc + 32] = c02[r];
                if (oc + 48 < NFFT) C[(size_t)orow0*NFFT + oc + 48] = c03[r];
            }
            if (orow0 + 16 < GM){
                if (oc      < NFFT) C[(size_t)(orow0+16)*NFFT + oc]      = c10[r];
                if (oc + 16 < NFFT) C[(size_t)(orow0+16)*NFFT + oc + 16] = c11[r];
                if (oc + 32 < NFFT) C[(size_t)(orow0+16)*NFFT + oc + 32] = c12[r];
                if (oc + 48 < NFFT) C[(size_t)(orow0+16)*NFFT + oc + 48] = c13[r];
            }
        }
    }
}

// ---------- overlap-add, float4: 4 outputs/thread (wsum==2 in cropped interior) ----------
__global__ __launch_bounds__(256) void k_ola(const float* __restrict__ frames, float* __restrict__ out){
    int gid = blockIdx.x*256 + threadIdx.x;
    if (gid >= 2*BB*(LL/4)) return;
    int o4 = (gid % (LL/4))*4;
    int rb = gid / (LL/4);                 // beam*BB + b
    int i  = o4 + HOP;                     // mult of 4; r in {0,4,...,156}
    int t1 = i / HOP;
    int r  = i - t1*HOP;
    const float4* fb = (const float4*)(frames + (size_t)rb*TT*NFFT);
    float4 a = fb[(t1*NFFT + r) >> 2];
    float4 b = fb[((t1-1)*NFFT + r + HOP) >> 2];
    ((float4*)out)[gid] = make_float4(0.5f*(a.x+b.x), 0.5f*(a.y+b.y), 0.5f*(a.z+b.z), 0.5f*(a.w+b.w));
}

extern "C" void kernel_launch(void* const* d_in, const int* in_sizes, int n_in,
                              void* d_out, int out_size, void* d_ws, size_t ws_size,
                              hipStream_t stream){
    const float* in  = (const float*)d_in[0];   // [B, L, C] fp32
    const float* win = (const float*)d_in[1];   // [320] fp32
    float* ws = (float*)d_ws;
    // ws (floats): mean 32 | invmax 8 | htab 2576 | pad -> header 3072
    //              | S1 (2,578,576) | S2 (2,578,576) | S (10,314,304)   total ~62 MB
    // R23: S1/S2 now bf16-packed (short4/elem) — use only half their regions.
    // aliases: part -> S1 head (dead before k_anorm); Ahi/Alo -> S1+S2 (dead after k_gstft);
    //          Bts + Bt -> head of d_out (dead until k_ola fully overwrites; NOT in S — R13 bug);
    //          A_ir -> S (post-scan); frames -> S1/S2 (post-pack)
    float* mean   = ws;
    float* invmax = ws + 32;
    float* htab   = ws + 48;
    float* S1     = ws + 3072;
    size_t nS1 = (size_t)2*BB*FB*TT;            // 2,578,576 floats per region (half used now)
    float* S2 = S1 + nS1;
    float* S  = S2 + nS1;                       // 10,314,304 floats
    float* part = S1;
    short* Ahi = (short*)S1;                    // 8*4*160320 = 5,130,240 shorts
    short* Alo = Ahi + (size_t)BB*CC*NPAD;      // total 10,260,480 shorts <= S1+S2 (10,314,304 short-equiv)
    short* Bts = (short*)d_out;                 // 245,760 shorts (= 122,880 floats)
    short* Bt  = (short*)((float*)d_out + 131072); // 225,280 shorts at float-offset 131072 (16B aligned)
    short* A  = (short*)S;                      // irfft A: 16016*704 bf16
    float* frames = S1;                         // 16016*320 floats over dead S1+S2

    k_genstats<<<dim3(BB*RBLK + (NGEN + 255)/256), dim3(256), 0, stream>>>(in, part, win, htab, Bts, Bt);
    k_stats2<<<dim3(BB), dim3(128), 0, stream>>>(part, mean, invmax);
    k_anorm<<<dim3((BB*(NPAD/8) + 255)/256), dim3(256), 0, stream>>>(in, mean, invmax, Ahi, Alo);
    k_gstft<<<dim3(BB*TP*CC/128, 2), dim3(512), 0, stream>>>(Ahi, Alo, Bts, S);
    k_scan<<<dim3(BB*FB), dim3(512), 0, stream>>>(S, htab, (short*)S1, (short*)S2);
    k_pack<<<dim3(512), dim3(256), 0, stream>>>((const short*)S1, (const short*)S2, A);
    k_gemm<<<dim3((NFFT + 127)/128, (GM + 127)/128), dim3(512), 0, stream>>>(A, Bt, frames);
    k_ola<<<dim3((2*BB*(LL/4) + 255)/256), dim3(256), 0, stream>>>(frames, (float*)d_out);
}

// Round 11
// 188.899 us; speedup vs baseline: 1.0111x; 1.0004x over previous
//
#include <hip/hip_runtime.h>
#include <hip/hip_bf16.h>
#include <math.h>

#define BB 8
#define LL 160000
#define CC 4
#define NFFT 320
#define HOP 160
#define FB 161          // rfft bins
#define TT 1001         // frames
#define TP 1024         // padded frames per batch (t-slots) for STFT GEMM
#define RBLK 128        // stats blocks per batch
#define PI_D 3.14159265358979323846
#define NPAD 160320     // reflect-padded samples per (b,c): p in [-160, 160159]

#define KWARM 4         // warm-up frames; tail weight 0.05^5 ~ 3e-7 rel << bf16 error floor (4.9e-4)

#define GM 16016        // irfft GEMM M = 2*BB*TT rows (beam,b,t)
#define KSEC 352        // irfft padded K per split-section (322 used)
#define LDK 704         // irfft A/Bt leading dim = 2 sections
#define KT 11           // irfft K-tiles of 32 per section
#define NGEN (2*FB*CC + 384*640)        // R24: Bt gen moved out of k_genstats
#define PACK_BLK 512
#define ZERO_BLK 2500                   // 2*BB*LL/4 float4 / 256 = 2500 exact
#define GENBT_BLK 880                   // NFFT*LDK / 256 = 880 exact
// R24: frames round-trip ELIMINATED. out[rb][t*160+n-160] += 0.5*frames[rb][t][n]
//      (each frames elem feeds exactly one output; 0.5(a+b) == 0.5a+0.5b bit-exact)
//      -> k_gemm epilogue atomicAdds 0.5*val into d_out; k_ola deleted. Bt moved to
//      S-region tail (S+8.0M floats; A ends at 5.64M) and generated LATE (ranged
//      blocks in k_pack, after k_gstft freed d_out's Bts/Bt head); d_out zeroed by
//      k_pack's zero-range blocks. Net: -41MB traffic +10MB zero, -1 launch.
// R23: bf16-packed S1/S2 (bit-identical A, half traffic); k_gemm grid (3,126)->L2;
//      k_gen merged into k_stats1.
// R22: k_gstft 128x192, 2 blocks/CU — NEUTRAL (phase-economics model retired;
//      k_gstft's ~42us bound is not barriers/tile/vmcnt). Structure frozen.
// R21: MFMA issue must stay acc-rotating (per-acc grouping stalls matrix pipe).
// R20: k_scan full-strip 2 outputs/thread; k_gemm 3-buffer ring.
// R14 lesson: LDS DMA staging is a latency-decoupling pipeline — do not remove.
// LIFETIME: Bts in d_out head (dead after k_gstft; zeroed before k_gemm). Bt in
// S-tail (written by k_pack's genBt range, read by k_gemm; S spectrogram dead
// after k_scan, A occupies only first 5.64M floats of S).

typedef __attribute__((ext_vector_type(8))) short bf16x8;
typedef __attribute__((ext_vector_type(4))) float f32x4;

__device__ __forceinline__ void ldsdma16(const short* g, short* l){
    __builtin_amdgcn_global_load_lds((const __attribute__((address_space(1))) void*)g,
                                     (__attribute__((address_space(3))) void*)l, 16, 0, 0);
}

__device__ __forceinline__ float2 cmulf(float2 a, float2 b){           // a*b
    return make_float2(a.x*b.x - a.y*b.y, a.x*b.y + a.y*b.x);
}
__device__ __forceinline__ float2 cmulcj(float2 a, float2 b){          // a*conj(b)
    return make_float2(a.x*b.x + a.y*b.y, a.y*b.x - a.x*b.y);
}
__device__ __forceinline__ float2 cjmul(float2 a, float2 b){           // conj(a)*b
    return make_float2(a.x*b.x + a.y*b.y, a.x*b.y - a.y*b.x);
}
__device__ __forceinline__ float2 csub(float2 a, float2 b){ return make_float2(a.x-b.x, a.y-b.y); }
__device__ __forceinline__ float2 cscale(float2 a, float s){ return make_float2(a.x*s, a.y*s); }
__device__ __forceinline__ float2 cdivf(float2 a, float2 b){           // a/b
    float inv = 1.0f/(b.x*b.x + b.y*b.y);
    return make_float2((a.x*b.x + a.y*b.y)*inv, (a.y*b.x - a.x*b.y)*inv);
}
__device__ __forceinline__ short bf_hi(float v){
    __hip_bfloat16 h = __float2bfloat16(v);
    short s; __builtin_memcpy(&s, &h, 2); return s;
}
__device__ __forceinline__ short bf_lo(float v){
    __hip_bfloat16 h = __float2bfloat16(v);
    float r = v - __bfloat162float(h);
    __hip_bfloat16 l = __float2bfloat16(r);
    short s; __builtin_memcpy(&s, &l, 2); return s;
}

// ---------- merged DAG heads: stats1 (blocks < BB*RBLK) | htab+Bts gen (rest) ----------
__global__ __launch_bounds__(256) void k_genstats(const float* __restrict__ in, float* __restrict__ part,
        const float* __restrict__ win, float* __restrict__ htab, short* __restrict__ Bts){
    __shared__ float4 s4[256];
    __shared__ float4 mn4[256];
    __shared__ float4 mx4[256];
    int tid = threadIdx.x;
    if (blockIdx.x < BB*RBLK){
        int b = blockIdx.x / RBLK, chunk = blockIdx.x % RBLK;
        const float4* p = (const float4*)(in + (size_t)b*LL*CC);
        const int per = LL / RBLK;
        int start = chunk*per;
        float4 s  = make_float4(0.f,0.f,0.f,0.f);
        float4 mn = make_float4( 3.4e38f, 3.4e38f, 3.4e38f, 3.4e38f);
        float4 mx = make_float4(-3.4e38f,-3.4e38f,-3.4e38f,-3.4e38f);
        for (int i = start + tid; i < start + per; i += 256){
            float4 v = p[i];
            s.x += v.x; s.y += v.y; s.z += v.z; s.w += v.w;
            mn.x = fminf(mn.x, v.x); mn.y = fminf(mn.y, v.y); mn.z = fminf(mn.z, v.z); mn.w = fminf(mn.w, v.w);
            mx.x = fmaxf(mx.x, v.x); mx.y = fmaxf(mx.y, v.y); mx.z = fmaxf(mx.z, v.z); mx.w = fmaxf(mx.w, v.w);
        }
        s4[tid] = s; mn4[tid] = mn; mx4[tid] = mx;
        __syncthreads();
        for (int st = 128; st >= 1; st >>= 1){
            if (tid < st){
                float4 a = s4[tid], c = s4[tid+st];
                s4[tid] = make_float4(a.x+c.x, a.y+c.y, a.z+c.z, a.w+c.w);
                float4 d = mn4[tid], e = mn4[tid+st];
                mn4[tid] = make_float4(fminf(d.x,e.x), fminf(d.y,e.y), fminf(d.z,e.z), fminf(d.w,e.w));
                float4 f = mx4[tid], g = mx4[tid+st];
                mx4[tid] = make_float4(fmaxf(f.x,g.x), fmaxf(f.y,g.y), fmaxf(f.z,g.z), fmaxf(f.w,g.w));
            }
            __syncthreads();
        }
        if (tid == 0){
            float* dst = part + (size_t)(b*RBLK + chunk)*12;
            float4 a = s4[0], d = mn4[0], f = mx4[0];
            dst[0]=a.x; dst[1]=a.y; dst[2]=a.z; dst[3]=a.w;
            dst[4]=d.x; dst[5]=d.y; dst[6]=d.z; dst[7]=d.w;
            dst[8]=f.x; dst[9]=f.y; dst[10]=f.z; dst[11]=f.w;
        }
        return;
    }
    int gid = (blockIdx.x - BB*RBLK)*256 + tid;
    const float W0 = (float)(2.0*PI_D/320.0);
    if (gid < 2*FB*CC){
        int i = gid;
        int c = i & 3;
        int k = (i >> 2) % FB;
        int m = i / (FB*CC);
        double coef = 2.0*PI_D*50.0*0.027*sin(40.0*PI_D/180.0)/340.0;
        double sgn = (m == 0) ? -1.0 : 1.0;
        double ph = sgn*coef*(double)k*(double)c;
        double s, c2;
        sincos(ph, &s, &c2);
        ((float2*)htab)[i] = make_float2((float)c2, (float)s);
        return;
    }
    gid -= 2*FB*CC;
    if (gid < 384*640){
        int col = gid / 640, kk = gid % 640;
        int n = (kk >= 320) ? kk - 320 : kk;
        int sec = (kk >= 320) ? 1 : 0;
        float v = 0.f;
        if (col < 2*FB){
            int k = col >> 1;
            int mr = (k*n) % 320;                    // exact reduction
            float s, co; sincosf(W0*(float)mr, &s, &co);
            v = win[n] * ((col & 1) ? -s : co);
        }
        Bts[gid] = sec ? bf_lo(v) : bf_hi(v);
    }
}

// ---------- stage 2: finalize mean + invmax per batch ----------
__global__ __launch_bounds__(128) void k_stats2(const float* __restrict__ part,
                                                float* __restrict__ mean, float* __restrict__ invmax){
    __shared__ float4 s4[128];
    __shared__ float4 mn4[128];
    __shared__ float4 mx4[128];
    int b = blockIdx.x, tid = threadIdx.x;
    const float* src = part + (size_t)(b*RBLK + tid)*12;
    s4[tid]  = make_float4(src[0], src[1], src[2], src[3]);
    mn4[tid] = make_float4(src[4], src[5], src[6], src[7]);
    mx4[tid] = make_float4(src[8], src[9], src[10], src[11]);
    __syncthreads();
    for (int st = 64; st >= 1; st >>= 1){
        if (tid < st){
            float4 a = s4[tid], c = s4[tid+st];
            s4[tid] = make_float4(a.x+c.x, a.y+c.y, a.z+c.z, a.w+c.w);
            float4 d = mn4[tid], e = mn4[tid+st];
            mn4[tid] = make_float4(fminf(d.x,e.x), fminf(d.y,e.y), fminf(d.z,e.z), fminf(d.w,e.w));
            float4 f = mx4[tid], g = mx4[tid+st];
            mx4[tid] = make_float4(fmaxf(f.x,g.x), fmaxf(f.y,g.y), fmaxf(f.z,g.z), fmaxf(f.w,g.w));
        }
        __syncthreads();
    }
    if (tid == 0){
        float4 sum = s4[0], mn = mn4[0], mx = mx4[0];
        float m0 = sum.x*(1.0f/LL), m1 = sum.y*(1.0f/LL), m2 = sum.z*(1.0f/LL), m3 = sum.w*(1.0f/LL);
        mean[b*4+0]=m0; mean[b*4+1]=m1; mean[b*4+2]=m2; mean[b*4+3]=m3;
        float a0 = fmaxf(mx.x - m0, m0 - mn.x);
        float a1 = fmaxf(mx.y - m1, m1 - mn.y);
        float a2 = fmaxf(mx.z - m2, m2 - mn.z);
        float a3 = fmaxf(mx.w - m3, m3 - mn.w);
        invmax[b] = 1.0f / fmaxf(fmaxf(a0, a1), fmaxf(a2, a3));
    }
}

// ---------- A-normalize (R19): coalesced — thread = 8 consecutive samples x 4 channels ----------
__global__ __launch_bounds__(256) void k_anorm(const float* __restrict__ in,
        const float* __restrict__ mean, const float* __restrict__ invmax,
        short* __restrict__ Ahi, short* __restrict__ Alo){
    int gid = blockIdx.x*256 + threadIdx.x;
    if (gid >= BB*(NPAD/8)) return;
    int p8 = gid % (NPAD/8);
    int b  = gid / (NPAD/8);
    float4 mc = *(const float4*)&mean[b*4];
    float iv = invmax[b];
    const float4* px = (const float4*)(in + (size_t)b*LL*CC);   // [LL][4ch]
    bf16x8 h0{}, h1{}, h2{}, h3{}, l0{}, l1{}, l2{}, l3{};
    #pragma unroll
    for (int j = 0; j < 8; ++j){
        int p = p8*8 + j - 160;
        int m2 = p < 0 ? -p : (p >= LL ? 2*LL - 2 - p : p);
        float4 v = px[m2];
        float v0 = (v.x - mc.x)*iv, v1 = (v.y - mc.y)*iv;
        float v2 = (v.z - mc.z)*iv, v3 = (v.w - mc.w)*iv;
        h0[j] = bf_hi(v0); l0[j] = bf_lo(v0);
        h1[j] = bf_hi(v1); l1[j] = bf_lo(v1);
        h2[j] = bf_hi(v2); l2[j] = bf_lo(v2);
        h3[j] = bf_hi(v3); l3[j] = bf_lo(v3);
    }
    size_t o = (size_t)(b*4)*NPAD + (size_t)p8*8;
    *(bf16x8*)&Ahi[o]          = h0;  *(bf16x8*)&Alo[o]          = l0;
    *(bf16x8*)&Ahi[o +   NPAD] = h1;  *(bf16x8*)&Alo[o +   NPAD] = l1;
    *(bf16x8*)&Ahi[o + 2*NPAD] = h2;  *(bf16x8*)&Alo[o + 2*NPAD] = l2;
    *(bf16x8*)&Ahi[o + 3*NPAD] = h3;  *(bf16x8*)&Alo[o + 3*NPAD] = l3;
}

// ---------- STFT as MFMA GEMM (R22, frozen): 128x192 tile, 8 waves ----------
// S out layout: complex S[b][k][h][t] (h = channel-pair), float4 per (b,k,h,t)
__global__ __launch_bounds__(512, 4) void k_gstft(const short* __restrict__ Ahi, const short* __restrict__ Alo,
        const short* __restrict__ Bts, float* __restrict__ S){
    __shared__ short stage[40960];           // 80 KB: 2 buffers x 20480 shorts
    int tid = threadIdx.x;
    int row0 = blockIdx.x*128;               // over b*TP*CC rows
    int col0 = blockIdx.y*192;               // 2 col-blocks cover 384 >= 322
    int b  = row0 >> 12;                     // TP*CC = 4096 rows per batch
    int t0 = (row0 & 4095) >> 2;             // in {0,32,...,992} — always < TT
    int wave = tid >> 6, lane = tid & 63;
    int wm = wave >> 1, wn = wave & 1;       // 4x2 wave grid: 32 rows x 96 cols each
    int l15 = lane & 15, quad = lane >> 4;
    int chunk = (tid & 3) ^ ((tid >> 3) & 3);
    int tq4 = tid >> 2;
    int rowA = tq4;                          // A rows 0..127, channel = row&3
    int tls = t0 + (rowA >> 2); if (tls >= TT) tls = TT - 1;
    size_t gao = (size_t)(b*4 + (rowA & 3))*NPAD + (size_t)tls*160 + chunk*8;
    const short* src0 = Ahi + gao;
    const short* src1 = Alo + gao;
    const short* src2 = Bts + (size_t)(col0 + tq4)*640 + chunk*8;
    const short* src3 = (tid < 256)
        ? Bts + (size_t)(col0 + 128 + tq4)*640 + chunk*8
        : Bts + (size_t)(col0 + ((tid - 256) >> 2))*640 + 320 + chunk*8;
    const short* src4 = Bts + (size_t)(col0 + 64 + tq4)*640 + 320 + chunk*8;
    short* lw = stage + wave*512;            // + j*4096 + buffer offset
    int sw  = (l15 >> 1) & 3;
    int c0r = (quad ^ sw) * 8;
    int ra0 = (wm*32 + l15)*32 + c0r;        // A frag 0; frag 1 at +512; Al at +4096
    int rbB = (wn*96 + l15)*32 + c0r;        // B frag j at +8192 (hi) / +14336 (lo) + j*512
    f32x4 c00 = {0.f,0.f,0.f,0.f}, c01 = c00, c02 = c00, c03 = c00, c04 = c00, c05 = c00;
    f32x4 c10 = c00, c11 = c00, c12 = c00, c13 = c00, c14 = c00, c15 = c00;

    #define STG(kt_, off_) do{ int ko_ = (kt_)*32; \
        ldsdma16(src0 + ko_, lw + (off_));          \
        ldsdma16(src1 + ko_, lw + (off_) + 4096);   \
        ldsdma16(src2 + ko_, lw + (off_) + 8192);   \
        ldsdma16(src3 + ko_, lw + (off_) + 12288);  \
        ldsdma16(src4 + ko_, lw + (off_) + 16384);  \
    }while(0)

    STG(0, 0);                               // 2-deep prologue
    STG(1, 20480);
    #pragma unroll
    for (int kt = 0; kt < 10; ++kt){
        int offc = (kt & 1) ? 20480 : 0;
        if (kt < 9) asm volatile("s_waitcnt vmcnt(5)" ::: "memory");
        else        asm volatile("s_waitcnt vmcnt(0)" ::: "memory");
        __builtin_amdgcn_s_barrier();        // buf[kt&1] ready
        bf16x8 a0h = *(bf16x8*)&stage[offc + ra0];
        bf16x8 a1h = *(bf16x8*)&stage[offc + ra0 + 512];
        bf16x8 a0l = *(bf16x8*)&stage[offc + 4096 + ra0];
        bf16x8 a1l = *(bf16x8*)&stage[offc + 4096 + ra0 + 512];
        bf16x8 b0h = *(bf16x8*)&stage[offc + 8192 + rbB];
        bf16x8 b1h = *(bf16x8*)&stage[offc + 8192 + rbB + 512];
        bf16x8 b2h = *(bf16x8*)&stage[offc + 8192 + rbB + 1024];
        bf16x8 b3h = *(bf16x8*)&stage[offc + 8192 + rbB + 1536];
        bf16x8 b4h = *(bf16x8*)&stage[offc + 8192 + rbB + 2048];
        bf16x8 b5h = *(bf16x8*)&stage[offc + 8192 + rbB + 2560];
        // group1: hh + lh, acc-rotating
        c00 = __builtin_amdgcn_mfma_f32_16x16x32_bf16(a0h, b0h, c00, 0, 0, 0);
        c01 = __builtin_amdgcn_mfma_f32_16x16x32_bf16(a0h, b1h, c01, 0, 0, 0);
        c02 = __builtin_amdgcn_mfma_f32_16x16x32_bf16(a0h, b2h, c02, 0, 0, 0);
        c03 = __builtin_amdgcn_mfma_f32_16x16x32_bf16(a0h, b3h, c03, 0, 0, 0);
        c04 = __builtin_amdgcn_mfma_f32_16x16x32_bf16(a0h, b4h, c04, 0, 0, 0);
        c05 = __builtin_amdgcn_mfma_f32_16x16x32_bf16(a0h, b5h, c05, 0, 0, 0);
        c10 = __builtin_amdgcn_mfma_f32_16x16x32_bf16(a1h, b0h, c10, 0, 0, 0);
        c11 = __builtin_amdgcn_mfma_f32_16x16x32_bf16(a1h, b1h, c11, 0, 0, 0);
        c12 = __builtin_amdgcn_mfma_f32_16x16x32_bf16(a1h, b2h, c12, 0, 0, 0);
        c13 = __builtin_amdgcn_mfma_f32_16x16x32_bf16(a1h, b3h, c13, 0, 0, 0);
        c14 = __builtin_amdgcn_mfma_f32_16x16x32_bf16(a1h, b4h, c14, 0, 0, 0);
        c15 = __builtin_amdgcn_mfma_f32_16x16x32_bf16(a1h, b5h, c15, 0, 0, 0);
        c00 = __builtin_amdgcn_mfma_f32_16x16x32_bf16(a0l, b0h, c00, 0, 0, 0);
        c01 = __builtin_amdgcn_mfma_f32_16x16x32_bf16(a0l, b1h, c01, 0, 0, 0);
        c02 = __builtin_amdgcn_mfma_f32_16x16x32_bf16(a0l, b2h, c02, 0, 0, 0);
        c03 = __builtin_amdgcn_mfma_f32_16x16x32_bf16(a0l, b3h, c03, 0, 0, 0);
        c04 = __builtin_amdgcn_mfma_f32_16x16x32_bf16(a0l, b4h, c04, 0, 0, 0);
        c05 = __builtin_amdgcn_mfma_f32_16x16x32_bf16(a0l, b5h, c05, 0, 0, 0);
        c10 = __builtin_amdgcn_mfma_f32_16x16x32_bf16(a1l, b0h, c10, 0, 0, 0);
        c11 = __builtin_amdgcn_mfma_f32_16x16x32_bf16(a1l, b1h, c11, 0, 0, 0);
        c12 = __builtin_amdgcn_mfma_f32_16x16x32_bf16(a1l, b2h, c12, 0, 0, 0);
        c13 = __builtin_amdgcn_mfma_f32_16x16x32_bf16(a1l, b3h, c13, 0, 0, 0);
        c14 = __builtin_amdgcn_mfma_f32_16x16x32_bf16(a1l, b4h, c14, 0, 0, 0);
        c15 = __builtin_amdgcn_mfma_f32_16x16x32_bf16(a1l, b5h, c15, 0, 0, 0);
        // Bl reads (Bh registers die above)
        bf16x8 b0l = *(bf16x8*)&stage[offc + 14336 + rbB];
        bf16x8 b1l = *(bf16x8*)&stage[offc + 14336 + rbB + 512];
        bf16x8 b2l = *(bf16x8*)&stage[offc + 14336 + rbB + 1024];
        bf16x8 b3l = *(bf16x8*)&stage[offc + 14336 + rbB + 1536];
        bf16x8 b4l = *(bf16x8*)&stage[offc + 14336 + rbB + 2048];
        bf16x8 b5l = *(bf16x8*)&stage[offc + 14336 + rbB + 2560];
        asm volatile("s_waitcnt lgkmcnt(0)" ::: "memory");
        __builtin_amdgcn_sched_barrier(0);   // rule #18: pin ALL buffer reads before reuse barrier
        __builtin_amdgcn_s_barrier();        // all waves done reading buf[kt&1]
        if (kt < 8) STG(kt+2, offc);         // overwrite just-freed buffer
        // group2: hl
        c00 = __builtin_amdgcn_mfma_f32_16x16x32_bf16(a0h, b0l, c00, 0, 0, 0);
        c01 = __builtin_amdgcn_mfma_f32_16x16x32_bf16(a0h, b1l, c01, 0, 0, 0);
        c02 = __builtin_amdgcn_mfma_f32_16x16x32_bf16(a0h, b2l, c02, 0, 0, 0);
        c03 = __builtin_amdgcn_mfma_f32_16x16x32_bf16(a0h, b3l, c03, 0, 0, 0);
        c04 = __builtin_amdgcn_mfma_f32_16x16x32_bf16(a0h, b4l, c04, 0, 0, 0);
        c05 = __builtin_amdgcn_mfma_f32_16x16x32_bf16(a0h, b5l, c05, 0, 0, 0);
        c10 = __builtin_amdgcn_mfma_f32_16x16x32_bf16(a1h, b0l, c10, 0, 0, 0);
        c11 = __builtin_amdgcn_mfma_f32_16x16x32_bf16(a1h, b1l, c11, 0, 0, 0);
        c12 = __builtin_amdgcn_mfma_f32_16x16x32_bf16(a1h, b2l, c12, 0, 0, 0);
        c13 = __builtin_amdgcn_mfma_f32_16x16x32_bf16(a1h, b3l, c13, 0, 0, 0);
        c14 = __builtin_amdgcn_mfma_f32_16x16x32_bf16(a1h, b4l, c14, 0, 0, 0);
        c15 = __builtin_amdgcn_mfma_f32_16x16x32_bf16(a1h, b5l, c15, 0, 0, 0);
    }
    #undef STG
    // ---- epilogue: shfl-pair assembly, direct global store (no LDS) ----
    int tq  = t0 + wm*8 + quad;
    int kgb = (col0 >> 1) + wn*48 + (l15 >> 1);
    int h   = l15 & 1;
    float4* S4 = (float4*)S;
    #define EPI(cf, i_, j_) do{ \
        int t = tq + 4*(i_); \
        int kg = kgb + 8*(j_); \
        if (t < TT && kg < FB){ \
            float p0 = __shfl_xor(cf[0], 1); \
            float p1 = __shfl_xor(cf[1], 1); \
            float p2 = __shfl_xor(cf[2], 1); \
            float p3 = __shfl_xor(cf[3], 1); \
            float4 v = h ? make_float4(p2, cf[2], p3, cf[3]) \
                         : make_float4(cf[0], p0, cf[1], p1); \
            S4[((size_t)((b*FB + kg)*2 + h))*TT + t] = v; \
        } \
    }while(0)
    EPI(c00, 0, 0); EPI(c01, 0, 1); EPI(c02, 0, 2); EPI(c03, 0, 3); EPI(c04, 0, 4); EPI(c05, 0, 5);
    EPI(c10, 1, 0); EPI(c11, 1, 1); EPI(c12, 1, 2); EPI(c13, 1, 3); EPI(c14, 1, 4); EPI(c15, 1, 5);
    #undef EPI
}

// covariance recurrence, original weighted form (first-frame handling): R = a*R + wg*outer(X)
#define UPD(first) do{ \
    float aa = (first) ? 0.f : 0.05f; float wg = (first) ? 1.f : 0.95f; \
    float y0x=wg*x0.x, y0y=wg*x0.y, y1x=wg*x1.x, y1y=wg*x1.y; \
    float y2x=wg*x2.x, y2y=wg*x2.y, y3x=wg*x3.x, y3y=wg*x3.y; \
    d0 = aa*d0 + y0x*x0.x + y0y*x0.y; \
    d1 = aa*d1 + y1x*x1.x + y1y*x1.y; \
    d2 = aa*d2 + y2x*x2.x + y2y*x2.y; \
    d3 = aa*d3 + y3x*x3.x + y3y*x3.y; \
    r10.x = aa*r10.x + y1x*x0.x + y1y*x0.y;  r10.y = aa*r10.y + y1y*x0.x - y1x*x0.y; \
    r20.x = aa*r20.x + y2x*x0.x + y2y*x0.y;  r20.y = aa*r20.y + y2y*x0.x - y2x*x0.y; \
    r30.x = aa*r30.x + y3x*x0.x + y3y*x0.y;  r30.y = aa*r30.y + y3y*x0.x - y3x*x0.y; \
    r21.x = aa*r21.x + y2x*x1.x + y2y*x1.y;  r21.y = aa*r21.y + y2y*x1.x - y2x*x1.y; \
    r31.x = aa*r31.x + y3x*x1.x + y3y*x1.y;  r31.y = aa*r31.y + y3y*x1.x - y3x*x1.y; \
    r32.x = aa*r32.x + y3x*x2.x + y3y*x2.y;  r32.y = aa*r32.y + y3y*x2.x - y3x*x2.y; \
}while(0)

// Q-form (R19): Q = 0.05*Q + outer(X); Q = R/0.95 exactly when no first-frame is in
// the truncated window. The solve is scale-invariant in R -> outputs identical.
#define UPDQ do{ \
    d0 = 0.05f*d0 + x0.x*x0.x + x0.y*x0.y; \
    d1 = 0.05f*d1 + x1.x*x1.x + x1.y*x1.y; \
    d2 = 0.05f*d2 + x2.x*x2.x + x2.y*x2.y; \
    d3 = 0.05f*d3 + x3.x*x3.x + x3.y*x3.y; \
    r10.x = 0.05f*r10.x + x1.x*x0.x + x1.y*x0.y;  r10.y = 0.05f*r10.y + x1.y*x0.x - x1.x*x0.y; \
    r20.x = 0.05f*r20.x + x2.x*x0.x + x2.y*x0.y;  r20.y = 0.05f*r20.y + x2.y*x0.x - x2.x*x0.y; \
    r30.x = 0.05f*r30.x + x3.x*x0.x + x3.y*x0.y;  r30.y = 0.05f*r30.y + x3.y*x0.x - x3.x*x0.y; \
    r21.x = 0.05f*r21.x + x2.x*x1.x + x2.y*x1.y;  r21.y = 0.05f*r21.y + x2.y*x1.x - x2.x*x1.y; \
    r31.x = 0.05f*r31.x + x3.x*x1.x + x3.y*x1.y;  r31.y = 0.05f*r31.y + x3.y*x1.x - x3.x*x1.y; \
    r32.x = 0.05f*r32.x + x3.x*x2.x + x3.y*x2.y;  r32.y = 0.05f*r32.y + x3.y*x2.x - x3.x*x2.y; \
}while(0)

// ---------- scan (R20 + R23): full-strip, 2 outputs/thread, bf16-packed output ----------
__global__ __launch_bounds__(512) void k_scan(const float* __restrict__ S, const float* __restrict__ htab,
                      short* __restrict__ S1, short* __restrict__ S2){
    __shared__ float4 tile[2016];     // swizzled full strip (2*TT=2002 used; swz stays in-group)
    int bf = blockIdx.x;              // b*FB + f
    int f  = bf % FB;
    int tid = threadIdx.x;
    const float4* P0 = (const float4*)S + (size_t)(bf*2)*TT;
    const float4* P1 = P0 + TT;
    for (int i = tid; i < 2*TT; i += 512){
        int tt = i >> 1;
        tile[i ^ ((i>>4)&7)] = (i & 1) ? P1[tt] : P0[tt];   // interleave planes into tile
    }
    __syncthreads();
    int t0 = tid*2;
    if (t0 < TT){
        const float2* hp = (const float2*)htab;
        float2 ha0 = hp[f*4+0], ha1 = hp[f*4+1], ha2 = hp[f*4+2], ha3 = hp[f*4+3];
        float2 hb0 = hp[(FB+f)*4+0], hb1 = hp[(FB+f)*4+1], hb2 = hp[(FB+f)*4+2], hb3 = hp[(FB+f)*4+3];
        float d0=0,d1=0,d2=0,d3=0;
        float2 r10={0,0}, r20={0,0}, r30={0,0}, r21={0,0}, r31={0,0}, r32={0,0};
        float2 x0, x1, x2, x3;
        #define LOADX(tau_) do{ int i0_ = 2*(tau_); \
            float4 v0_ = tile[i0_ ^ ((i0_>>4)&7)]; \
            float4 v1_ = tile[(i0_+1) ^ (((i0_+1)>>4)&7)]; \
            x0 = make_float2(v0_.x, v0_.y); x1 = make_float2(v0_.z, v0_.w); \
            x2 = make_float2(v1_.x, v1_.y); x3 = make_float2(v1_.z, v1_.w); \
        }while(0)
        bool qform = (t0 >= KWARM + 1);   // no frame-0 special in any window
        int ts = t0 - KWARM; if (ts < 0) ts = 0;
        if (qform){
            #pragma unroll
            for (int u = 0; u < KWARM; ++u){ LOADX(ts + u); UPDQ; }
        } else {
            for (int tau = 0; tau < t0; ++tau){ LOADX(tau); UPD(tau == 0); }
        }
        short4* S1g = (short4*)S1 + (size_t)bf*TT;
        short4* S2g = (short4*)S2 + (size_t)bf*TT;
        #pragma unroll
        for (int j = 0; j < 2; ++j){
            int t = t0 + j;
            if (t >= TT) break;
            LOADX(t);
            if (qform) UPDQ; else UPD(t == 0);
            float trc = d0 + d1 + d2 + d3;
            float lam = trc * 0.25f;
            float e0 = d0 + lam, e1 = d1 + lam, e2 = d2 + lam, e3 = d3 + lam;
            float detP = e0*e1 - (r10.x*r10.x + r10.y*r10.y);
            float2 w00 = csub(cscale(r20, e1), cmulf(r10, r21));
            float2 w01 = csub(cscale(r30, e1), cmulf(r10, r31));
            float2 w10 = csub(cscale(r21, e0), cjmul(r10, r20));
            float2 w11 = csub(cscale(r31, e0), cjmul(r10, r30));
            float2 va = cjmul(r30, w00), vb = cjmul(r31, w10);
            float2 V10 = make_float2(va.x + vb.x, -(va.y + vb.y));
            float reV00 = r20.x*w00.x + r20.y*w00.y + r21.x*w10.x + r21.y*w10.y;
            float reV11 = r30.x*w01.x + r30.y*w01.y + r31.x*w11.x + r31.y*w11.y;
            float t00 = detP*e2 - reV00;
            float t11 = detP*e3 - reV11;
            float2 t10 = csub(cscale(r32, detP), V10);
            float detT = t00*t11 - (t10.x*t10.x + t10.y*t10.y);
            #pragma unroll
            for (int m = 0; m < 2; ++m){
                float2 h0 = m ? hb0 : ha0;
                float2 h1 = m ? hb1 : ha1;
                float2 h2 = m ? hb2 : ha2;
                float2 h3 = m ? hb3 : ha3;
                float2 g0 = csub(cscale(h0, e1), cjmul(r10, h1));
                float2 g1 = csub(cscale(h1, e0), cmulf(r10, h0));
                float2 ta = cmulf(r20, g0), tb = cmulf(r21, g1);
                float2 hh0 = make_float2(detP*h2.x - ta.x - tb.x, detP*h2.y - ta.y - tb.y);
                ta = cmulf(r30, g0); tb = cmulf(r31, g1);
                float2 hh1 = make_float2(detP*h3.x - ta.x - tb.x, detP*h3.y - ta.y - tb.y);
                float2 y20 = csub(cscale(hh0, t11), cjmul(t10, hh1));
                float2 y21 = csub(cscale(hh1, t00), cmulf(t10, hh0));
                float2 u20 = cscale(y20, detP), u21 = cscale(y21, detP);
                ta = cmulcj(y20, r20); tb = cmulcj(y21, r30);
                float2 q0 = make_float2(detT*h0.x - ta.x - tb.x, detT*h0.y - ta.y - tb.y);
                ta = cmulcj(y20, r21); tb = cmulcj(y21, r31);
                float2 q1 = make_float2(detT*h1.x - ta.x - tb.x, detT*h1.y - ta.y - tb.y);
                float2 u10 = csub(cscale(q0, e1), cjmul(r10, q1));
                float2 u11 = csub(cscale(q1, e0), cmulf(r10, q0));
                float2 den = cjmul(h0, u10), tmp;
                tmp = cjmul(h1, u11); den.x += tmp.x; den.y += tmp.y;
                tmp = cjmul(h2, u20); den.x += tmp.x; den.y += tmp.y;
                tmp = cjmul(h3, u21); den.x += tmp.x; den.y += tmp.y;
                float2 num = cjmul(u10, x0);
                tmp = cjmul(u11, x1); num.x += tmp.x; num.y += tmp.y;
                tmp = cjmul(u20, x2); num.x += tmp.x; num.y += tmp.y;
                tmp = cjmul(u21, x3); num.x += tmp.x; num.y += tmp.y;
                float2 s = cdivf(num, make_float2(den.x, -den.y));
                short4 pk;
                pk.x = bf_hi(s.x); pk.y = bf_hi(s.y);
                pk.z = bf_lo(s.x); pk.w = bf_lo(s.y);
                if (m) S2g[t] = pk; else S1g[t] = pk;
            }
        }
        #undef LOADX
    }
}

// ---------- pack (R24): transpose | zero d_out | gen Bt — block-ranged ----------
__global__ __launch_bounds__(256) void k_pack(const short* __restrict__ S1, const short* __restrict__ S2,
                                              short* __restrict__ A, float* __restrict__ outz,
                                              short* __restrict__ Bt, const float* __restrict__ win){
    int bid = blockIdx.x;
    int tid = threadIdx.x;
    if (bid < PACK_BLK){
        __shared__ short tile[32*708];    // row = t-in-tile, col = kk (hi 0..351 | lo 352..703)
        int tb = bid & 31, rb = bid >> 5;
        int t0 = tb*32;
        int beam = rb >> 3, b = rb & 7;
        const short4* Sp = (const short4*)(beam ? S2 : S1) + (size_t)b*FB*TT;
        for (int idx = tid; idx < 32*176; idx += 256){
            int bin = idx >> 5, tq = idx & 31;
            int t = t0 + tq;
            short4 s = make_short4(0, 0, 0, 0);
            if (bin < FB && t < TT) s = Sp[(size_t)bin*TT + t];
            int c0 = 2*bin;
            tile[tq*708 + c0]            = s.x;
            tile[tq*708 + c0 + 1]        = s.y;
            tile[tq*708 + KSEC + c0]     = s.z;
            tile[tq*708 + KSEC + c0 + 1] = s.w;
        }
        __syncthreads();
        for (int idx = tid; idx < 32*176; idx += 256){
            int tq = idx / 176, k4 = idx % 176;
            int t = t0 + tq;
            if (t < TT)
                *(short4*)&A[(size_t)(rb*TT + t)*LDK + k4*4] = *(short4*)&tile[tq*708 + k4*4];
        }
        return;
    }
    if (bid < PACK_BLK + ZERO_BLK){
        // zero d_out (Bts head dead after k_gstft); 640,000 float4 total
        int g = (bid - PACK_BLK)*256 + tid;
        ((float4*)outz)[g] = make_float4(0.f, 0.f, 0.f, 0.f);
        return;
    }
    // gen Bt into S-tail (R21 math: exact mod-320 + f32 sincosf)
    int gid = (bid - PACK_BLK - ZERO_BLK)*256 + tid;
    if (gid < NFFT*LDK){
        const float W0 = (float)(2.0*PI_D/320.0);
        int n = gid / LDK, kk = gid % LDK;
        int sec = (kk >= KSEC) ? 1 : 0;
        int kk2 = kk - (sec ? KSEC : 0);
        float v = 0.f;
        if (kk2 < 2*FB){
            int bin = kk2 >> 1;
            float c = ((bin == 0 || bin == 160) ? 1.0f : 2.0f) * (1.0f/320.0f);
            int mr = (bin*n) % 320;
            float s, co; sincosf(W0*(float)mr, &s, &co);
            v = (kk2 & 1) ? -c*s : c*co;
        }
        Bt[(size_t)n*LDK + kk] = sec ? bf_lo(v) : bf_hi(v);
    }
}

// ---------- irfft MFMA GEMM (R24): 3-buffer ring; OLA fused via atomicAdd ----------
// out[rb][t*160 + col - 160] += 0.5*val — each (row,col) product element feeds
// exactly one output sample; two contributors per sample (from col and col+160).
__global__ __launch_bounds__(512, 4) void k_gemm(const short* __restrict__ A, const short* __restrict__ Bt,
                                                 float* __restrict__ out){
    __shared__ short sb2[24576];           // 48 KB: 3 buffers x (A|B) x 4096 shorts
    int tid = threadIdx.x;
    int row0 = blockIdx.y * 128;
    int col0 = blockIdx.x * 128;
    int wave = tid >> 6, lane = tid & 63;
    int wm = wave >> 1, wn = wave & 1;     // 4x2 wave grid: 32 rows x 64 cols each
    int l15 = lane & 15, quad = lane >> 4;
    bool wlive = (col0 + wn*64) < NFFT;    // x=2,wn=1 waves are fully past NFFT
    int rowS  = wave*16 + (lane >> 2);
    int chunk = (lane & 3) ^ ((lane >> 3) & 3);
    int grS = row0 + rowS; if (grS >= GM) grS = GM - 1;       // clamp; stores guarded
    int grB = col0 + rowS; if (grB >= NFFT) grB = NFFT - 1;   // clamp; cols >=320 unused
    const short* gA = A  + (size_t)grS*LDK + chunk*8;
    const short* gB = Bt + (size_t)grB*LDK + chunk*8;
    short* lA = sb2 + wave*512;
    int sw  = (l15 >> 1) & 3;
    int c0r = (quad ^ sw) * 8;
    int ra0 = (wm*32 + l15)*32 + c0r;      // frag 1 at +512
    int rb0 = (wn*64 + l15)*32 + c0r;      // frag j at +j*512
    f32x4 c00 = {0.f,0.f,0.f,0.f}, c01 = c00, c02 = c00, c03 = c00;
    f32x4 c10 = c00, c11 = c00, c12 = c00, c13 = c00;

    #define KOF(s_, ka_, kb_) { int sg_ = ((s_) >= 22) ? 2 : ((s_) >= 11) ? 1 : 0; \
        int kt_ = (s_) - sg_*11; \
        ka_ = ((sg_ == 1) ? KSEC : 0) + kt_*32; \
        kb_ = ((sg_ == 2) ? KSEC : 0) + kt_*32; }
    #define STG2(s_, off_) do{ int ka_, kb_; KOF(s_, ka_, kb_); \
        ldsdma16(gA + ka_, lA + (off_));        \
        ldsdma16(gB + kb_, lA + (off_) + 4096); \
    }while(0)

    STG2(0, 0);                            // 2-deep prologue into ring slots 0,1
    STG2(1, 8192);
    #pragma unroll
    for (int s = 0; s < 33; ++s){
        int offc = (s % 3) * 8192;
        if (s < 32) asm volatile("s_waitcnt vmcnt(2)" ::: "memory");
        else        asm volatile("s_waitcnt vmcnt(0)" ::: "memory");
        __builtin_amdgcn_s_barrier();      // buf[s%3] ready; also: all s-1 reads done
        if (s < 31) STG2(s+2, ((s+2) % 3) * 8192);   // writes buf[(s-1)%3] — freed above
        bf16x8 a0{}, a1{}, b0{}, b1{}, b2{}, b3{};
        if (wlive){
            a0 = *(bf16x8*)&sb2[offc + ra0];
            a1 = *(bf16x8*)&sb2[offc + ra0 + 512];
            b0 = *(bf16x8*)&sb2[offc + 4096 + rb0];
            b1 = *(bf16x8*)&sb2[offc + 4096 + rb0 + 512];
            b2 = *(bf16x8*)&sb2[offc + 4096 + rb0 + 1024];
            b3 = *(bf16x8*)&sb2[offc + 4096 + rb0 + 1536];
            asm volatile("s_waitcnt lgkmcnt(0)" ::: "memory");
            __builtin_amdgcn_sched_barrier(0);
            c00 = __builtin_amdgcn_mfma_f32_16x16x32_bf16(a0, b0, c00, 0, 0, 0);
            c01 = __builtin_amdgcn_mfma_f32_16x16x32_bf16(a0, b1, c01, 0, 0, 0);
            c02 = __builtin_amdgcn_mfma_f32_16x16x32_bf16(a0, b2, c02, 0, 0, 0);
            c03 = __builtin_amdgcn_mfma_f32_16x16x32_bf16(a0, b3, c03, 0, 0, 0);
            c10 = __builtin_amdgcn_mfma_f32_16x16x32_bf16(a1, b0, c10, 0, 0, 0);
            c11 = __builtin_amdgcn_mfma_f32_16x16x32_bf16(a1, b1, c11, 0, 0, 0);
            c12 = __builtin_amdgcn_mfma_f32_16x16x32_bf16(a1, b2, c12, 0, 0, 0);
            c13 = __builtin_amdgcn_mfma_f32_16x16x32_bf16(a1, b3, c13, 0, 0, 0);
        }
    }
    #undef STG2
    #undef KOF
    if (wlive){
        #define OST(mm_, cc_, vv_) do{ \
            if ((mm_) < GM && (cc_) < NFFT){ \
                int rb_ = (mm_) / TT, t_ = (mm_) - rb_*TT; \
                int ii_ = t_*HOP + (cc_) - HOP; \
                if (ii_ >= 0 && ii_ < LL) \
                    atomicAdd(&out[(size_t)rb_*LL + ii_], 0.5f*(vv_)); \
            } }while(0)
        #pragma unroll
        for (int r = 0; r < 4; ++r){
            int m0 = row0 + wm*32 + quad*4 + r;
            int oc = col0 + wn*64 + l15;
            OST(m0,    oc,      c00[r]);
            OST(m0,    oc + 16, c01[r]);
            OST(m0,    oc + 32, c02[r]);
            OST(m0,    oc + 48, c03[r]);
            OST(m0+16, oc,      c10[r]);
            OST(m0+16, oc + 16, c11[r]);
            OST(m0+16, oc + 32, c12[r]);
            OST(m0+16, oc + 48, c13[r]);
        }
        #undef OST
    }
}

extern "C" void kernel_launch(void* const* d_in, const int* in_sizes, int n_in,
                              void* d_out, int out_size, void* d_ws, size_t ws_size,
                              hipStream_t stream){
    const float* in  = (const float*)d_in[0];   // [B, L, C] fp32
    const float* win = (const float*)d_in[1];   // [320] fp32
    float* ws = (float*)d_ws;
    // ws (floats): mean 32 | invmax 8 | htab 2576 | pad -> header 3072
    //              | S1 (2,578,576) | S2 (2,578,576) | S (10,314,304)   total ~62 MB
    // aliases: part -> S1 head (dead before k_anorm); Ahi/Alo -> S1+S2 (dead after
    // k_gstft); S1/S2 bf16-packed by k_scan (full regions); A -> S head (post-scan,
    // 5.64M floats); Bt -> S + 8.0M floats (written by k_pack genBt range, read by
    // k_gemm; spectrogram there dead after k_scan). Bts -> d_out head (dead after
    // k_gstft; d_out zeroed by k_pack zero range, then atomicAdd'ed by k_gemm).
    float* mean   = ws;
    float* invmax = ws + 32;
    float* htab   = ws + 48;
    float* S1     = ws + 3072;
    size_t nS1 = (size_t)2*BB*FB*TT;            // 2,578,576 floats per region
    float* S2 = S1 + nS1;
    float* S  = S2 + nS1;                       // 10,314,304 floats
    float* part = S1;
    short* Ahi = (short*)S1;                    // 8*4*160320 = 5,130,240 shorts
    short* Alo = Ahi + (size_t)BB*CC*NPAD;      // total 10,260,480 shorts <= S1+S2
    short* Bts = (short*)d_out;                 // 245,760 shorts (dead after k_gstft)
    short* A   = (short*)S;                     // irfft A: 16016*704 bf16 = 5,637,632 float-eq
    short* Bt  = (short*)(S + 8000000);         // 225,280 shorts in dead S-tail (16B aligned)

    k_genstats<<<dim3(BB*RBLK + (NGEN + 255)/256), dim3(256), 0, stream>>>(in, part, win, htab, Bts);
    k_stats2<<<dim3(BB), dim3(128), 0, stream>>>(part, mean, invmax);
    k_anorm<<<dim3((BB*(NPAD/8) + 255)/256), dim3(256), 0, stream>>>(in, mean, invmax, Ahi, Alo);
    k_gstft<<<dim3(BB*TP*CC/128, 2), dim3(512), 0, stream>>>(Ahi, Alo, Bts, S);
    k_scan<<<dim3(BB*FB), dim3(512), 0, stream>>>(S, htab, (short*)S1, (short*)S2);
    k_pack<<<dim3(PACK_BLK + ZERO_BLK + GENBT_BLK), dim3(256), 0, stream>>>(
        (const short*)S1, (const short*)S2, A, (float*)d_out, Bt, win);
    k_gemm<<<dim3((NFFT + 127)/128, (GM + 127)/128), dim3(512), 0, stream>>>(A, Bt, (float*)d_out);
}